// Round 8
// baseline (1996.480 us; speedup 1.0000x reference)
//
#include <hip/hip_runtime.h>
#include <stdint.h>
#include <stddef.h>

#define DIM    1024
#define NBATCH 8
#define SEQL   2048
#define JSUM   512

typedef unsigned long long ull;
typedef __attribute__((ext_vector_type(8))) __bf16 bf16x8;
typedef __attribute__((ext_vector_type(8))) short  short8;
typedef __attribute__((ext_vector_type(4))) float  floatx4;

__device__ __forceinline__ short f2bf(float f) {
  unsigned u = __builtin_bit_cast(unsigned, f);
  u = (u + 0x7fffu + ((u >> 16) & 1u)) >> 16;   // RNE
  return (short)u;
}
__device__ __forceinline__ float bf2f(short s) {
  unsigned u = ((unsigned)(unsigned short)s) << 16;
  return __builtin_bit_cast(float, u);
}

// NOTE: the intrinsic's imm-offset arg applies to BOTH global and LDS
// addresses — always pass 0 and do pointer arithmetic on both sides.
__device__ __forceinline__ void glds16(const short* g, short8* l) {
  __builtin_amdgcn_global_load_lds(
      (const __attribute__((address_space(1))) unsigned int*)g,
      (__attribute__((address_space(3))) unsigned int*)l, 16, 0, 0);
}

// Counted vmcnt wait (T4): never drain to 0 inside the K-loop.
#define VMCNT(n) do { asm volatile("s_waitcnt vmcnt(" #n ")" ::: "memory"); \
                      __builtin_amdgcn_sched_barrier(0); } while (0)

// Raw barrier WITHOUT the implicit s_waitcnt vmcnt(0) of __syncthreads().
// Safe because (a) every ds_read's consuming MFMA precedes the barrier
// (data dep forces lgkmcnt drain), (b) cross-wave LDS visibility of staged
// tiles is established by per-wave VMCNT(N) + this barrier.
__device__ __forceinline__ void barrier_raw() {
  asm volatile("" ::: "memory");
  __builtin_amdgcn_s_barrier();
  asm volatile("" ::: "memory");
}

// ---------------------------------------------------------------------------
// NT GEMM: C[m,n] = sum_k A[m,k]*B[n,k]. A: M x K row-major, B: N x K row-major.
// 128x128 tile, BK=32, **128 threads (2 waves), per-wave 128x64**.
//
// R0-R7 post-mortem: nothing saturates (MFMA 16%, VALU 10-30%, LDS-BW ~37%,
// HBM 9%) -> latency/sync-bound: waves convoy on the 2 barriers per K-tile
// with only ~200cy ds_read + ~80cy MFMA issue of work between them.
// Fix: double the work per sync per wave (32 MFMA + 12 ds_read per barrier
// pair) at UNCHANGED tile/grid/staging. acc = 128 VGPR; af loaded in 2
// halves keeps arch regs ~50-70 -> total ~190 <= 256 -> 2 waves/SIMD
// (R6's failure was total 260 > 256 -> 1 wave/SIMD).
//
// Loop mechanics = R3 (best measured): double-buffered LDS, stage t+2 at
// end of tile t, counted VMCNT(8) waits only tile t+1's loads.
// LDS 32 KiB/block -> 4 blocks/CU at 2 waves/SIMD.
// Requires K % 32 == 0 and K >= 64 (prologue stages 2 tiles).
// MODE 0: C bf16            MODE 1: C bf16 + bias[n]
// MODE 2: C bf16 + bias[m]  MODE 3: f32 scatter rows (+bias[n])
// SWIZ 1: gridDim.z==8; batch = lin&7 pins batch->XCD
// SWIZ 2: tm=bx, tn=by, bz=0 — A-panel sharers on one XCD (gridDim.x%8==0)
// LDS fragment-major: 16B block (k8,row) at k8*128+row; BK=32 -> k8 in 0..3.
// Measured conflict-free (SQ_LDS_BANK_CONFLICT = 0 across R0-R7).
// ---------------------------------------------------------------------------
template<int MODE, int SWIZ>
__global__ __launch_bounds__(128, 2)
void gemm_nt(const short* __restrict__ A, ull sA,
             const short* __restrict__ Bm, ull sB,
             short* __restrict__ Cb, ull sC,
             int N, int Kd,
             const float* __restrict__ bias,
             float* __restrict__ dst0, int t_lo, int t_hi, int outT,
             float* __restrict__ dstSp, int t_sp, int Spad)
{
  int tn, tm, bz;
  if (SWIZ == 1) {
    const unsigned gx = gridDim.x;
    ull lin = blockIdx.x + (ull)gx * (blockIdx.y + (ull)gridDim.y * blockIdx.z);
    bz = (int)(lin & 7);
    ull s = lin >> 3;
    tn = (int)(s % gx);
    tm = (int)(s / gx);
  } else {            // SWIZ == 2
    tm = blockIdx.x; tn = blockIdx.y; bz = 0;
  }

  A  += (ull)bz * sA;
  Bm += (ull)bz * sB;

  const int tid  = threadIdx.x;          // 0..127
  const int wave = tid >> 6, lane = tid & 63;

  __shared__ short8 ldsA[2][512];   // 2 x 8 KB: slot = k8*128 + row (k8 0..3)
  __shared__ short8 ldsB[2][512];   // 2 x 8 KB

  // Staging (8 glds / thread / K-tile): thread tid stages row tid of A and B,
  // k8 = c (c=0..3). Dest slot c*128 + tid (wave-contiguous: base + lane*16).
  const short* gA = A  + (long long)(tm * 128 + tid) * Kd;
  const short* gB = Bm + (long long)(tn * 128 + tid) * Kd;

  floatx4 acc[8][4];
#pragma unroll
  for (int i = 0; i < 8; i++)
#pragma unroll
    for (int j = 0; j < 4; j++) acc[i][j] = (floatx4)(0.0f);

  const int wn = wave * 64;      // per-wave: all 128 m-rows x 64 n-cols
  const int fr = lane & 15;      // fragment row/col select
  const int fq = lane >> 4;      // k8 select (0..3) within the 32-K tile

  const int nt = Kd >> 5;

  // Issue one K-tile's staging into buffer b, advance global pointers.
  auto issue = [&](int b) {
#pragma unroll
    for (int c = 0; c < 4; c++) glds16(gA + c * 8, &ldsA[b][c * 128 + tid]);
#pragma unroll
    for (int c = 0; c < 4; c++) glds16(gB + c * 8, &ldsB[b][c * 128 + tid]);
    gA += 32; gB += 32;
  };

  issue(0);            // 8 outstanding (tile 0)
  issue(1);            // 16 outstanding (tile 1)
  VMCNT(8);            // tile 0 landed (tile 1's 8 still in flight)
  barrier_raw();

  const int ab = fq * 128 + fr;        // A slot base (+ mt*16)
  const int bb = fq * 128 + wn + fr;   // B slot base (+ n2*16)

  for (int t = 0; t < nt; t++) {
    const short8* LA = ldsA[t & 1];
    const short8* LB = ldsB[t & 1];

    bf16x8 bv4[4], af[4];
#pragma unroll
    for (int n2 = 0; n2 < 4; n2++)
      bv4[n2] = __builtin_bit_cast(bf16x8, LB[bb + n2 * 16]);
    // m-half 0: frags 0..3
#pragma unroll
    for (int mt = 0; mt < 4; mt++)
      af[mt] = __builtin_bit_cast(bf16x8, LA[ab + mt * 16]);
#pragma unroll
    for (int mt = 0; mt < 4; mt++)
#pragma unroll
      for (int n2 = 0; n2 < 4; n2++)
        acc[mt][n2] = __builtin_amdgcn_mfma_f32_16x16x32_bf16(
            af[mt], bv4[n2], acc[mt][n2], 0, 0, 0);
    // m-half 1: frags 4..7 (reuse af regs to cap liveness)
#pragma unroll
    for (int mt = 0; mt < 4; mt++)
      af[mt] = __builtin_bit_cast(bf16x8, LA[ab + (mt + 4) * 16]);
#pragma unroll
    for (int mt = 0; mt < 4; mt++)
#pragma unroll
      for (int n2 = 0; n2 < 4; n2++)
        acc[mt + 4][n2] = __builtin_amdgcn_mfma_f32_16x16x32_bf16(
            af[mt], bv4[n2], acc[mt + 4][n2], 0, 0, 0);

    barrier_raw();     // every wave done READING buf (t&1) -> safe to overwrite
    if (t + 2 < nt)      { issue(t & 1); VMCNT(8); }  // wait = t+1's loads only
    else if (t + 1 < nt) { VMCNT(0); }                // drain final tile
    barrier_raw();     // tile t+1 visible to all waves
  }

  // Epilogue.  C/D layout: col = lane&15, row = (lane>>4)*4 + reg  [m89]
  if (MODE == 3) {
    // Tiles never straddle batches (Spad % 128 == 0): derive batch once.
    const int bbatch = (tm * 128) / Spad;
    const int rb0    = tm * 128 - bbatch * Spad + fq * 4;
#pragma unroll
    for (int mt = 0; mt < 8; mt++) {
#pragma unroll
      for (int n2 = 0; n2 < 4; n2++) {
        const int col = tn * 128 + wn + n2 * 16 + fr;
#pragma unroll
        for (int r = 0; r < 4; r++) {
          const int tt = rb0 + mt * 16 + r;
          float v = acc[mt][n2][r] + bias[col];
          if (tt >= t_lo && tt < t_hi)
            dst0[((size_t)bbatch * outT + (tt - t_lo)) * DIM + col] = v;
          else if (tt == t_sp)
            dstSp[(size_t)bbatch * DIM + col] = v;
        }
      }
    }
  } else {
    short* C = Cb + (ull)bz * sC;
#pragma unroll
    for (int mt = 0; mt < 8; mt++) {
#pragma unroll
      for (int n2 = 0; n2 < 4; n2++) {
        const int col = tn * 128 + wn + n2 * 16 + fr;
        float bn = (MODE == 1) ? bias[col] : 0.0f;
#pragma unroll
        for (int r = 0; r < 4; r++) {
          const int row = tm * 128 + mt * 16 + fq * 4 + r;
          float v = acc[mt][n2][r] + bn;
          if (MODE == 2) v += bias[row];
          C[(size_t)row * N + col] = f2bf(v);
        }
      }
    }
  }
}

// ---------------------------------------------------------------------------
// In-place row softmax over bf16 score rows. Row length Spad, valid k < S.
// Vectorized short8 load/store (G13: scalar bf16 ~2-2.5x slower).
// ---------------------------------------------------------------------------
__global__ __launch_bounds__(256)
void softmax_rows(short* __restrict__ SA, int Spad, int S, float scale)
{
  __shared__ float buf[2176];
  __shared__ float red[8];
  const int t = blockIdx.x, b = blockIdx.y;
  short* row = SA + ((size_t)b * Spad + t) * Spad;
  const int tid = threadIdx.x;
  const int nv = S >> 3;                  // full short8 groups

  float mx = -1e30f;
  for (int g = tid; g < nv; g += 256) {
    short8 v = ((const short8*)row)[g];
#pragma unroll
    for (int j = 0; j < 8; j++) {
      float f = bf2f(v[j]) * scale;
      buf[g * 8 + j] = f;
      mx = fmaxf(mx, f);
    }
  }
  for (int i = (nv << 3) + tid; i < S; i += 256) {
    float f = bf2f(row[i]) * scale;
    buf[i] = f;
    mx = fmaxf(mx, f);
  }
  for (int off = 32; off; off >>= 1) mx = fmaxf(mx, __shfl_down(mx, off, 64));
  if ((tid & 63) == 0) red[tid >> 6] = mx;
  __syncthreads();
  if (tid == 0) {
    float m = red[0];
    for (int w = 1; w < 4; w++) m = fmaxf(m, red[w]);
    red[0] = m;
  }
  __syncthreads();
  mx = red[0];

  float sum = 0.f;
  for (int i = tid; i < S; i += 256) {
    float e = __expf(buf[i] - mx);
    buf[i] = e;
    sum += e;
  }
  for (int off = 32; off; off >>= 1) sum += __shfl_down(sum, off, 64);
  if ((tid & 63) == 0) red[4 + (tid >> 6)] = sum;
  __syncthreads();
  if (tid == 0) red[4] = 1.0f / (red[4] + red[5] + red[6] + red[7]);
  __syncthreads();
  const float rinv = red[4];

  for (int g = tid; g < nv; g += 256) {
    short8 o;
#pragma unroll
    for (int j = 0; j < 8; j++) o[j] = f2bf(buf[g * 8 + j] * rinv);
    ((short8*)row)[g] = o;
  }
  for (int i = (nv << 3) + tid; i < S; i += 256) row[i] = f2bf(buf[i] * rinv);
  for (int i = S + tid; i < Spad; i += 256) row[i] = 0;
}

// ---------------------------------------------------------------------------
__global__ __launch_bounds__(256)
void wtrans(const float* __restrict__ W, short* __restrict__ WT)
{
  __shared__ float tile[32][33];
  const int bn = blockIdx.x * 32, bk = blockIdx.y * 32;
  const int tx = threadIdx.x & 31, ty = threadIdx.x >> 5;  // 32 x 8
#pragma unroll
  for (int j = 0; j < 4; j++)
    tile[ty + j * 8][tx] = W[(size_t)(bk + ty + j * 8) * DIM + bn + tx];
  __syncthreads();
#pragma unroll
  for (int j = 0; j < 4; j++)
    WT[(size_t)(bn + ty + j * 8) * DIM + bk + tx] = f2bf(tile[tx][ty + j * 8]);
}

// ---------------------------------------------------------------------------
__global__ __launch_bounds__(256)
void assemble0(const float* __restrict__ seg0, short* __restrict__ X)
{
  const int Spad = 2176;
  const int b = blockIdx.y;
  const size_t lin = ((size_t)blockIdx.x * 256 + threadIdx.x) * 4;
  const int t = (int)(lin >> 10), d = (int)(lin & 1023);
  float4 v = make_float4(0.f, 0.f, 0.f, 0.f);
  if (t >= 1 && t <= SEQL)
    v = *(const float4*)(seg0 + ((size_t)b * SEQL + (t - 1)) * DIM + d);
  union { short s[4]; ull u; } o;
  o.s[0] = f2bf(v.x); o.s[1] = f2bf(v.y); o.s[2] = f2bf(v.z); o.s[3] = f2bf(v.w);
  *(ull*)(X + (size_t)b * Spad * DIM + lin) = o.u;
}

__global__ __launch_bounds__(256)
void assembleS(const float* __restrict__ seg1, const float* __restrict__ prompt,
               short* __restrict__ X)
{
  const int Spad = 640;
  const int b = blockIdx.y;
  const size_t lin = ((size_t)blockIdx.x * 256 + threadIdx.x) * 4;
  const int t = (int)(lin >> 10), d = (int)(lin & 1023);
  float4 v = make_float4(0.f, 0.f, 0.f, 0.f);
  if (t == 0 || t == JSUM + 1)
    v = *(const float4*)(prompt + d);
  else if (t >= 1 && t <= JSUM)
    v = *(const float4*)(seg1 + ((size_t)b * SEQL + (t - 1)) * DIM + d);
  union { short s[4]; ull u; } o;
  o.s[0] = f2bf(v.x); o.s[1] = f2bf(v.y); o.s[2] = f2bf(v.z); o.s[3] = f2bf(v.w);
  *(ull*)(X + (size_t)b * Spad * DIM + lin) = o.u;
}

__global__ __launch_bounds__(256)
void assemble1(const float* __restrict__ seg0, const float* __restrict__ seg1,
               const float* __restrict__ P1, short* __restrict__ X)
{
  const int Spad = 2176;
  const int b = blockIdx.y;
  const size_t lin = ((size_t)blockIdx.x * 256 + threadIdx.x) * 4;
  const int t = (int)(lin >> 10), d = (int)(lin & 1023);
  float4 v = make_float4(0.f, 0.f, 0.f, 0.f);
  if (t < 32)
    v = *(const float4*)(seg0 + ((size_t)b * SEQL + (SEQL - 32 + t)) * DIM + d);
  else if (t == 32 || t == 2081)
    v = *(const float4*)(P1 + (size_t)b * DIM + d);
  else if (t >= 33 && t <= 2080)
    v = *(const float4*)(seg1 + ((size_t)b * SEQL + (t - 33)) * DIM + d);
  union { short s[4]; ull u; } o;
  o.s[0] = f2bf(v.x); o.s[1] = f2bf(v.y); o.s[2] = f2bf(v.z); o.s[3] = f2bf(v.w);
  *(ull*)(X + (size_t)b * Spad * DIM + lin) = o.u;
}

// ---------------------------------------------------------------------------
__global__ __launch_bounds__(256)
void mem_proj(const float* __restrict__ Sb, const float* __restrict__ M1,
              const float* __restrict__ Wq_mem, const float* __restrict__ bq_mem,
              const float* __restrict__ Wk_mem, const float* __restrict__ bk_mem,
              float* __restrict__ Qn, float* __restrict__ Kp)
{
  const int n = blockIdx.x * 256 + threadIdx.x;
  const int b = blockIdx.y;
  const int w = blockIdx.z;
  const float* x    = w ? M1 : Sb;
  const float* W    = w ? Wk_mem : Wq_mem;
  const float* bias = w ? bk_mem : bq_mem;
  float* o          = w ? Kp : Qn;
  const float* xr = x + (size_t)b * DIM;
  float s = bias[n];
  for (int k = 0; k < DIM; k++) s += xr[k] * W[(size_t)k * DIM + n];
  o[(size_t)b * DIM + n] = s;
}

__global__ __launch_bounds__(256)
void mem_attn(const float* __restrict__ Qn, const float* __restrict__ Kp,
              const float* __restrict__ M1, float* __restrict__ P1, float scale)
{
  __shared__ float red[256];
  __shared__ float w8[8];
  const int b = blockIdx.x, tid = threadIdx.x;
  for (int bp = 0; bp < NBATCH; bp++) {
    float p = 0.f;
    for (int k = tid; k < DIM; k += 256)
      p += Qn[(size_t)b * DIM + k] * Kp[(size_t)bp * DIM + k];
    red[tid] = p; __syncthreads();
    for (int off = 128; off; off >>= 1) {
      if (tid < off) red[tid] += red[tid + off];
      __syncthreads();
    }
    if (tid == 0) w8[bp] = red[0] * scale;
    __syncthreads();
  }
  if (tid == 0) {
    float m = w8[0];
    for (int i = 1; i < NBATCH; i++) m = fmaxf(m, w8[i]);
    float s = 0.f;
    for (int i = 0; i < NBATCH; i++) { w8[i] = __expf(w8[i] - m); s += w8[i]; }
    for (int i = 0; i < NBATCH; i++) w8[i] /= s;
  }
  __syncthreads();
  for (int d = tid; d < DIM; d += 256) {
    float a = 0.f;
    for (int bp = 0; bp < NBATCH; bp++) a += w8[bp] * M1[(size_t)bp * DIM + d];
    P1[(size_t)b * DIM + d] = a;
  }
}

// ---------------------------------------------------------------------------
extern "C" void kernel_launch(void* const* d_in, const int* in_sizes, int n_in,
                              void* d_out, int out_size, void* d_ws, size_t ws_size,
                              hipStream_t stream)
{
  const float* seg0   = (const float*)d_in[0];
  const float* seg1   = (const float*)d_in[1];
  const float* prompt = (const float*)d_in[2];
  const float* Wq_mem = (const float*)d_in[3];
  const float* bq_mem = (const float*)d_in[4];
  const float* Wk_mem = (const float*)d_in[5];
  const float* bk_mem = (const float*)d_in[6];
  const float* Wq     = (const float*)d_in[7];
  const float* bq     = (const float*)d_in[8];
  const float* Wk     = (const float*)d_in[9];
  const float* bk     = (const float*)d_in[10];
  const float* Wv     = (const float*)d_in[11];
  const float* bv     = (const float*)d_in[12];
  const float* Wo     = (const float*)d_in[13];
  const float* bo     = (const float*)d_in[14];
  float* outp = (float*)d_out;

  const int   SPMAX = 2176;
  const size_t WSZ  = (size_t)DIM * DIM * 2;
  const size_t XSZ  = (size_t)NBATCH * SPMAX * DIM * 2;
  const size_t SASZ = (size_t)NBATCH * SPMAX * SPMAX * 2;
  const size_t VSZ  = (size_t)NBATCH * DIM * 4;

  char* p = (char*)d_ws;
  short* WqT = (short*)p; p += WSZ;
  short* WkT = (short*)p; p += WSZ;
  short* WvT = (short*)p; p += WSZ;
  short* WoT = (short*)p; p += WSZ;
  short* X   = (short*)p; p += XSZ;
  short* Qb  = (short*)p; p += XSZ;
  short* Kb  = (short*)p; p += XSZ;
  short* Vt  = (short*)p; p += XSZ;
  short* Ctx = (short*)p; p += XSZ;
  short* SA  = (short*)p; p += SASZ;
  float* M1b = (float*)p; p += VSZ;
  float* Sb  = (float*)p; p += VSZ;
  float* Qn  = (float*)p; p += VSZ;
  float* Kp  = (float*)p; p += VSZ;
  float* P1  = (float*)p; p += VSZ;

  const float scale = 0.03125f;   // 1/sqrt(1024)
  dim3 blk(256, 1, 1);
  dim3 blkG(128, 1, 1);

  auto run_backbone = [&](int Spad, int S,
                          float* o_dst, int t_lo, int t_hi, int outT,
                          float* o_sp, int t_sp) {
    const int MT = NBATCH * Spad / 128;
    // Q = X Wq^T + bq   (SWIZ=2: A-panel sharers on one XCD; MT % 8 == 0)
    gemm_nt<1, 2><<<dim3(MT, DIM / 128, 1), blkG, 0, stream>>>(
        X, 0ULL, WqT, 0ULL, Qb, 0ULL, DIM, DIM, bq,
        nullptr, 0, 0, 0, nullptr, -1, Spad);
    // K = X Wk^T + bk
    gemm_nt<1, 2><<<dim3(MT, DIM / 128, 1), blkG, 0, stream>>>(
        X, 0ULL, WkT, 0ULL, Kb, 0ULL, DIM, DIM, bk,
        nullptr, 0, 0, 0, nullptr, -1, Spad);
    // Vt[b] (D x Spad) = NT(WvT, X_b) + bv[m]   (batch->XCD swizzle)
    gemm_nt<2, 1><<<dim3(Spad / 128, DIM / 128, NBATCH), blkG, 0, stream>>>(
        WvT, 0ULL, X, (ull)Spad * DIM,
        Vt, (ull)DIM * Spad, Spad, DIM, bv,
        nullptr, 0, 0, 0, nullptr, -1, Spad);
    // scores[b] = Q_b K_b^T   (batch->XCD swizzle)
    gemm_nt<0, 1><<<dim3(Spad / 128, Spad / 128, NBATCH), blkG, 0, stream>>>(
        Qb, (ull)Spad * DIM, Kb, (ull)Spad * DIM,
        SA, (ull)Spad * Spad, Spad, DIM, nullptr,
        nullptr, 0, 0, 0, nullptr, -1, Spad);
    softmax_rows<<<dim3(Spad, NBATCH), blk, 0, stream>>>(SA, Spad, S, scale);
    // ctx[b] = attn_b Vt_b^T   (batch->XCD swizzle)
    gemm_nt<0, 1><<<dim3(DIM / 128, Spad / 128, NBATCH), blkG, 0, stream>>>(
        SA, (ull)Spad * Spad, Vt, (ull)DIM * Spad,
        Ctx, (ull)Spad * DIM, DIM, Spad, nullptr,
        nullptr, 0, 0, 0, nullptr, -1, Spad);
    // H = ctx Wo^T + bo, scattered to outputs
    gemm_nt<3, 2><<<dim3(MT, DIM / 128, 1), blkG, 0, stream>>>(
        Ctx, 0ULL, WoT, 0ULL, nullptr, 0ULL, DIM, DIM, bo,
        o_dst, t_lo, t_hi, outT, o_sp, t_sp, Spad);
  };

  wtrans<<<dim3(32, 32), blk, 0, stream>>>(Wq, WqT);
  wtrans<<<dim3(32, 32), blk, 0, stream>>>(Wk, WkT);
  wtrans<<<dim3(32, 32), blk, 0, stream>>>(Wv, WvT);
  wtrans<<<dim3(32, 32), blk, 0, stream>>>(Wo, WoT);

  // Phase 0: backbone([P0, seg0, P0])  S=2050, Spad=2176
  assemble0<<<dim3(2176, NBATCH), blk, 0, stream>>>(seg0, X);
  run_backbone(2176, 2050, outp, 33, 2049, 2016, M1b, 2049);

  // Phase S: summarize(seg1)  S=514, Spad=640
  assembleS<<<dim3(640, NBATCH), blk, 0, stream>>>(seg1, prompt, X);
  run_backbone(640, 514, nullptr, 0, 0, 0, Sb, JSUM);

  // Memory attention (exact f32)
  mem_proj<<<dim3(DIM / 256, NBATCH, 2), blk, 0, stream>>>(
      Sb, M1b, Wq_mem, bq_mem, Wk_mem, bk_mem, Qn, Kp);
  mem_attn<<<dim3(NBATCH), blk, 0, stream>>>(Qn, Kp, M1b, P1, scale);

  // Phase 1: backbone([seg0[-32:], P1, seg1, P1])  S=2082, Spad=2176
  assemble1<<<dim3(2176, NBATCH), blk, 0, stream>>>(seg0, seg1, P1, X);
  run_backbone(2176, 2082, outp + (size_t)NBATCH * 2016 * DIM,
               33, 2081, 2048, nullptr, -1);
}

// Round 9
// 1698.937 us; speedup vs baseline: 1.1751x; 1.1751x over previous
//
#include <hip/hip_runtime.h>
#include <stdint.h>
#include <stddef.h>

#define DIM    1024
#define NBATCH 8
#define SEQL   2048
#define JSUM   512
#define SPMAX  2304

typedef unsigned long long ull;
typedef __attribute__((ext_vector_type(8))) __bf16 bf16x8;
typedef __attribute__((ext_vector_type(8))) short  short8;
typedef __attribute__((ext_vector_type(4))) float  floatx4;

__device__ __forceinline__ short f2bf(float f) {
  unsigned u = __builtin_bit_cast(unsigned, f);
  u = (u + 0x7fffu + ((u >> 16) & 1u)) >> 16;   // RNE
  return (short)u;
}
__device__ __forceinline__ float bf2f(short s) {
  unsigned u = ((unsigned)(unsigned short)s) << 16;
  return __builtin_bit_cast(float, u);
}

// NOTE: the intrinsic's imm-offset arg applies to BOTH global and LDS
// addresses — always pass 0 and do pointer arithmetic on both sides.
__device__ __forceinline__ void glds16(const short* g, short8* l) {
  __builtin_amdgcn_global_load_lds(
      (const __attribute__((address_space(1))) unsigned int*)g,
      (__attribute__((address_space(3))) unsigned int*)l, 16, 0, 0);
}

// Counted vmcnt wait (T4): never drain to 0 inside the K-loop.
#define VMCNT(n) do { asm volatile("s_waitcnt vmcnt(" #n ")" ::: "memory"); \
                      __builtin_amdgcn_sched_barrier(0); } while (0)

// Raw barrier WITHOUT the implicit s_waitcnt vmcnt(0) of __syncthreads().
__device__ __forceinline__ void barrier_raw() {
  asm volatile("" ::: "memory");
  __builtin_amdgcn_s_barrier();
  asm volatile("" ::: "memory");
}

// ---------------------------------------------------------------------------
// NT GEMM: C[m,n] = sum_k A[m,k]*B[n,k]. A: M x K row-major, B: N x K row-major.
//
// m201-template port (verified 1563 TF@4k structure): 256x256 tile, BK=64,
// 512 threads (8 waves, 2M x 4N, per-wave 128x64, acc[8][4] = 128 VGPR).
// LDS 128 KiB: 2 K-tile buffers x (A 32K + B 32K), fragment-major slot
// (k8,row) = k8*256 + row — conflict-free (measured 0, R0-R8) and
// glds-linear-compatible, so NO xor-swizzle needed.
//
// Per K-tile: 4 fine phases (ks x m-half), each:
//   { ds_read frags ; issue ONE 16KB half-tile stage (2 glds/thread) ;
//     barrier ; setprio(1) ; 16 MFMA ; setprio(0) ; [vmcnt guard] ; barrier }
// Stage units of tile t+1 issued in order A0,B0,A1,B1 during t's phases
// 0..3; consumed next tile in the SAME order. Guards (derived):
//   p1-end vmcnt(4): queue=[A1(t),B1(t),A0',B0'] -> A1,B1 landed for p2/p3.
//   p3-end vmcnt(4): queue=[A0',B0',A1',B1']     -> A0',B0' landed for next p0.
// Each guard is per-wave; the following barrier extends it to all waves.
// >=4 loads always in flight; vmcnt(0) only at the last tile's p1.
// Overwrite safety: stages write buf^1, fully consumed before the boundary
// barrier (reads complete before their MFMAs, which precede the barrier).
//
// __launch_bounds__(512, 2): cap 256 regs -> 2 waves/SIMD -> whole block
// resident (1 block/CU at 128 KiB LDS).
// Requires M%256==0, N%256==0, K%64==0, K>=64.
// MODE 0: C bf16            MODE 1: C bf16 + bias[n]
// MODE 2: C bf16 + bias[m]  MODE 3: f32 scatter rows (+bias[n])
// SWIZ 1: gridDim.z==8; batch = lin&7 pins batch->XCD
// SWIZ 2: tm=blockIdx.x, tn=blockIdx.y, bz=0
// ---------------------------------------------------------------------------
template<int MODE, int SWIZ>
__global__ __launch_bounds__(512, 2)
void gemm_nt(const short* __restrict__ A, ull sA,
             const short* __restrict__ Bm, ull sB,
             short* __restrict__ Cb, ull sC,
             int N, int Kd,
             const float* __restrict__ bias,
             float* __restrict__ dst0, int t_lo, int t_hi, int outT,
             float* __restrict__ dstSp, int t_sp, int Spad)
{
  int tn, tm, bz;
  if (SWIZ == 1) {
    const unsigned gx = gridDim.x;
    ull lin = blockIdx.x + (ull)gx * (blockIdx.y + (ull)gridDim.y * blockIdx.z);
    bz = (int)(lin & 7);
    ull s = lin >> 3;
    tn = (int)(s % gx);
    tm = (int)(s / gx);
  } else {            // SWIZ == 2
    tm = blockIdx.x; tn = blockIdx.y; bz = 0;
  }

  A  += (ull)bz * sA;
  Bm += (ull)bz * sB;

  const int tid  = threadIdx.x;          // 0..511
  const int wave = tid >> 6, lane = tid & 63;

  __shared__ short8 ldsA[2][2048];   // 2 x 32 KB: slot = k8*256 + row, k8 0..7
  __shared__ short8 ldsB[2][2048];   // 2 x 32 KB

  // Staging thread map: slot s in {tid, tid+512} (+1024 for k-half 1):
  //   k8 = (s>>8) [+4h], row = s&255.  Dest = wave-uniform base + lane*16 OK.
  const int r0  = tid & 255;
  const int k80 = tid >> 8;                         // 0..1
  const short* pA = A  + (long long)(tm * 256 + r0) * Kd + k80 * 8;
  const short* pB = Bm + (long long)(tn * 256 + r0) * Kd + k80 * 8;

  floatx4 acc[8][4];
#pragma unroll
  for (int i = 0; i < 8; i++)
#pragma unroll
    for (int j = 0; j < 4; j++) acc[i][j] = (floatx4)(0.0f);

  const int wm = (wave >> 2) * 128;   // 2 M-halves of waves
  const int wn = (wave & 3) * 64;     // 4 N-quarters of waves
  const int fr = lane & 15;           // fragment row/col select
  const int fq = lane >> 4;           // k8 select (0..3) within a 32-K step

  const int nt = Kd >> 6;             // BK = 64

  // Prologue: stage tile 0's 4 units in guard order A0,B0,A1,B1.
  glds16(pA,      &ldsA[0][tid]);
  glds16(pA + 16, &ldsA[0][tid + 512]);
  glds16(pB,      &ldsB[0][tid]);
  glds16(pB + 16, &ldsB[0][tid + 512]);
  glds16(pA + 32, &ldsA[0][1024 + tid]);
  glds16(pA + 48, &ldsA[0][1024 + tid + 512]);
  glds16(pB + 32, &ldsB[0][1024 + tid]);
  glds16(pB + 48, &ldsB[0][1024 + tid + 512]);
  VMCNT(4);            // A0,B0 landed (A1,B1 still in flight)
  barrier_raw();

  for (int t = 0; t < nt; t++) {
    const short8* LA = ldsA[t & 1];
    const short8* LB = ldsB[t & 1];
    const int  nb   = (t + 1) & 1;
    const int  koff = (t + 1) * 64;
    const bool stg  = (t + 1) < nt;

    bf16x8 af[4], bv[4];

    // ---- phase 0: ks=0, m-half 0   (+stage A-half0 of t+1) ----
    {
      const int ka = fq * 256;
#pragma unroll
      for (int mt = 0; mt < 4; mt++)
        af[mt] = __builtin_bit_cast(bf16x8, LA[ka + wm + mt * 16 + fr]);
#pragma unroll
      for (int n2 = 0; n2 < 4; n2++)
        bv[n2] = __builtin_bit_cast(bf16x8, LB[ka + wn + n2 * 16 + fr]);
      if (stg) {
        glds16(pA + koff,      &ldsA[nb][tid]);
        glds16(pA + koff + 16, &ldsA[nb][tid + 512]);
      }
      barrier_raw();
      __builtin_amdgcn_s_setprio(1);
#pragma unroll
      for (int mt = 0; mt < 4; mt++)
#pragma unroll
        for (int n2 = 0; n2 < 4; n2++)
          acc[mt][n2] = __builtin_amdgcn_mfma_f32_16x16x32_bf16(
              af[mt], bv[n2], acc[mt][n2], 0, 0, 0);
      __builtin_amdgcn_s_setprio(0);
      barrier_raw();
    }

    // ---- phase 1: ks=0, m-half 1   (+stage B-half0) ----
    {
      const int ka = fq * 256;
#pragma unroll
      for (int mt = 0; mt < 4; mt++)
        af[mt] = __builtin_bit_cast(bf16x8, LA[ka + wm + 64 + mt * 16 + fr]);
      if (stg) {
        glds16(pB + koff,      &ldsB[nb][tid]);
        glds16(pB + koff + 16, &ldsB[nb][tid + 512]);
      }
      barrier_raw();
      __builtin_amdgcn_s_setprio(1);
#pragma unroll
      for (int mt = 0; mt < 4; mt++)
#pragma unroll
        for (int n2 = 0; n2 < 4; n2++)
          acc[4 + mt][n2] = __builtin_amdgcn_mfma_f32_16x16x32_bf16(
              af[mt], bv[n2], acc[4 + mt][n2], 0, 0, 0);
      __builtin_amdgcn_s_setprio(0);
      if (stg) VMCNT(4); else VMCNT(0);   // guard A1,B1 of tile t
      barrier_raw();
    }

    // ---- phase 2: ks=1, m-half 0   (+stage A-half1) ----
    {
      const int ka = (fq + 4) * 256;
#pragma unroll
      for (int mt = 0; mt < 4; mt++)
        af[mt] = __builtin_bit_cast(bf16x8, LA[ka + wm + mt * 16 + fr]);
#pragma unroll
      for (int n2 = 0; n2 < 4; n2++)
        bv[n2] = __builtin_bit_cast(bf16x8, LB[ka + wn + n2 * 16 + fr]);
      if (stg) {
        glds16(pA + koff + 32, &ldsA[nb][1024 + tid]);
        glds16(pA + koff + 48, &ldsA[nb][1024 + tid + 512]);
      }
      barrier_raw();
      __builtin_amdgcn_s_setprio(1);
#pragma unroll
      for (int mt = 0; mt < 4; mt++)
#pragma unroll
        for (int n2 = 0; n2 < 4; n2++)
          acc[mt][n2] = __builtin_amdgcn_mfma_f32_16x16x32_bf16(
              af[mt], bv[n2], acc[mt][n2], 0, 0, 0);
      __builtin_amdgcn_s_setprio(0);
      barrier_raw();
    }

    // ---- phase 3: ks=1, m-half 1   (+stage B-half1) ----
    {
      const int ka = (fq + 4) * 256;
#pragma unroll
      for (int mt = 0; mt < 4; mt++)
        af[mt] = __builtin_bit_cast(bf16x8, LA[ka + wm + 64 + mt * 16 + fr]);
      if (stg) {
        glds16(pB + koff + 32, &ldsB[nb][1024 + tid]);
        glds16(pB + koff + 48, &ldsB[nb][1024 + tid + 512]);
      }
      barrier_raw();
      __builtin_amdgcn_s_setprio(1);
#pragma unroll
      for (int mt = 0; mt < 4; mt++)
#pragma unroll
        for (int n2 = 0; n2 < 4; n2++)
          acc[4 + mt][n2] = __builtin_amdgcn_mfma_f32_16x16x32_bf16(
              af[mt], bv[n2], acc[4 + mt][n2], 0, 0, 0);
      __builtin_amdgcn_s_setprio(0);
      if (stg) VMCNT(4);                  // guard next tile's A0,B0
      barrier_raw();
    }
  }

  // Epilogue.  C/D layout: col = lane&15, row = (lane>>4)*4 + reg  [m89]
  // acc[mf][n2]: row-in-wave = (mf>>2)*64 + (mf&3)*16, col-in-wave = n2*16.
  if (MODE == 3) {
    // Tiles never straddle batches (Spad % 256 == 0): derive batch once.
    const int bb  = (tm * 256) / Spad;
    const int rb0 = tm * 256 - bb * Spad + wm + fq * 4;
#pragma unroll
    for (int mf = 0; mf < 8; mf++) {
#pragma unroll
      for (int n2 = 0; n2 < 4; n2++) {
        const int col = tn * 256 + wn + n2 * 16 + fr;
#pragma unroll
        for (int r = 0; r < 4; r++) {
          const int tt = rb0 + (mf >> 2) * 64 + (mf & 3) * 16 + r;
          float v = acc[mf][n2][r] + bias[col];
          if (tt >= t_lo && tt < t_hi)
            dst0[((size_t)bb * outT + (tt - t_lo)) * DIM + col] = v;
          else if (tt == t_sp)
            dstSp[(size_t)bb * DIM + col] = v;
        }
      }
    }
  } else {
    short* C = Cb + (ull)bz * sC;
#pragma unroll
    for (int mf = 0; mf < 8; mf++) {
#pragma unroll
      for (int n2 = 0; n2 < 4; n2++) {
        const int col = tn * 256 + wn + n2 * 16 + fr;
        float bn = (MODE == 1) ? bias[col] : 0.0f;
#pragma unroll
        for (int r = 0; r < 4; r++) {
          const int row = tm * 256 + wm + (mf >> 2) * 64 + (mf & 3) * 16 + fq * 4 + r;
          float v = acc[mf][n2][r] + bn;
          if (MODE == 2) v += bias[row];
          C[(size_t)row * N + col] = f2bf(v);
        }
      }
    }
  }
}

// ---------------------------------------------------------------------------
// In-place row softmax over bf16 score rows. Row length Spad, valid k < S.
// Vectorized short8 load/store (G13).
// ---------------------------------------------------------------------------
__global__ __launch_bounds__(256)
void softmax_rows(short* __restrict__ SA, int Spad, int S, float scale)
{
  __shared__ float buf[SPMAX];
  __shared__ float red[8];
  const int t = blockIdx.x, b = blockIdx.y;
  short* row = SA + ((size_t)b * Spad + t) * Spad;
  const int tid = threadIdx.x;
  const int nv = S >> 3;                  // full short8 groups

  float mx = -1e30f;
  for (int g = tid; g < nv; g += 256) {
    short8 v = ((const short8*)row)[g];
#pragma unroll
    for (int j = 0; j < 8; j++) {
      float f = bf2f(v[j]) * scale;
      buf[g * 8 + j] = f;
      mx = fmaxf(mx, f);
    }
  }
  for (int i = (nv << 3) + tid; i < S; i += 256) {
    float f = bf2f(row[i]) * scale;
    buf[i] = f;
    mx = fmaxf(mx, f);
  }
  for (int off = 32; off; off >>= 1) mx = fmaxf(mx, __shfl_down(mx, off, 64));
  if ((tid & 63) == 0) red[tid >> 6] = mx;
  __syncthreads();
  if (tid == 0) {
    float m = red[0];
    for (int w = 1; w < 4; w++) m = fmaxf(m, red[w]);
    red[0] = m;
  }
  __syncthreads();
  mx = red[0];

  float sum = 0.f;
  for (int i = tid; i < S; i += 256) {
    float e = __expf(buf[i] - mx);
    buf[i] = e;
    sum += e;
  }
  for (int off = 32; off; off >>= 1) sum += __shfl_down(sum, off, 64);
  if ((tid & 63) == 0) red[4 + (tid >> 6)] = sum;
  __syncthreads();
  if (tid == 0) red[4] = 1.0f / (red[4] + red[5] + red[6] + red[7]);
  __syncthreads();
  const float rinv = red[4];

  for (int g = tid; g < nv; g += 256) {
    short8 o;
#pragma unroll
    for (int j = 0; j < 8; j++) o[j] = f2bf(buf[g * 8 + j] * rinv);
    ((short8*)row)[g] = o;
  }
  for (int i = (nv << 3) + tid; i < S; i += 256) row[i] = f2bf(buf[i] * rinv);
  for (int i = S + tid; i < Spad; i += 256) row[i] = 0;
}

// ---------------------------------------------------------------------------
__global__ __launch_bounds__(256)
void wtrans(const float* __restrict__ W, short* __restrict__ WT)
{
  __shared__ float tile[32][33];
  const int bn = blockIdx.x * 32, bk = blockIdx.y * 32;
  const int tx = threadIdx.x & 31, ty = threadIdx.x >> 5;  // 32 x 8
#pragma unroll
  for (int j = 0; j < 4; j++)
    tile[ty + j * 8][tx] = W[(size_t)(bk + ty + j * 8) * DIM + bn + tx];
  __syncthreads();
#pragma unroll
  for (int j = 0; j < 4; j++)
    WT[(size_t)(bn + ty + j * 8) * DIM + bk + tx] = f2bf(tile[tx][ty + j * 8]);
}

// ---------------------------------------------------------------------------
__global__ __launch_bounds__(256)
void assemble0(const float* __restrict__ seg0, short* __restrict__ X)
{
  const int Spad = SPMAX;
  const int b = blockIdx.y;
  const size_t lin = ((size_t)blockIdx.x * 256 + threadIdx.x) * 4;
  const int t = (int)(lin >> 10), d = (int)(lin & 1023);
  float4 v = make_float4(0.f, 0.f, 0.f, 0.f);
  if (t >= 1 && t <= SEQL)
    v = *(const float4*)(seg0 + ((size_t)b * SEQL + (t - 1)) * DIM + d);
  union { short s[4]; ull u; } o;
  o.s[0] = f2bf(v.x); o.s[1] = f2bf(v.y); o.s[2] = f2bf(v.z); o.s[3] = f2bf(v.w);
  *(ull*)(X + (size_t)b * Spad * DIM + lin) = o.u;
}

__global__ __launch_bounds__(256)
void assembleS(const float* __restrict__ seg1, const float* __restrict__ prompt,
               short* __restrict__ X)
{
  const int Spad = 768;
  const int b = blockIdx.y;
  const size_t lin = ((size_t)blockIdx.x * 256 + threadIdx.x) * 4;
  const int t = (int)(lin >> 10), d = (int)(lin & 1023);
  float4 v = make_float4(0.f, 0.f, 0.f, 0.f);
  if (t == 0 || t == JSUM + 1)
    v = *(const float4*)(prompt + d);
  else if (t >= 1 && t <= JSUM)
    v = *(const float4*)(seg1 + ((size_t)b * SEQL + (t - 1)) * DIM + d);
  union { short s[4]; ull u; } o;
  o.s[0] = f2bf(v.x); o.s[1] = f2bf(v.y); o.s[2] = f2bf(v.z); o.s[3] = f2bf(v.w);
  *(ull*)(X + (size_t)b * Spad * DIM + lin) = o.u;
}

__global__ __launch_bounds__(256)
void assemble1(const float* __restrict__ seg0, const float* __restrict__ seg1,
               const float* __restrict__ P1, short* __restrict__ X)
{
  const int Spad = SPMAX;
  const int b = blockIdx.y;
  const size_t lin = ((size_t)blockIdx.x * 256 + threadIdx.x) * 4;
  const int t = (int)(lin >> 10), d = (int)(lin & 1023);
  float4 v = make_float4(0.f, 0.f, 0.f, 0.f);
  if (t < 32)
    v = *(const float4*)(seg0 + ((size_t)b * SEQL + (SEQL - 32 + t)) * DIM + d);
  else if (t == 32 || t == 2081)
    v = *(const float4*)(P1 + (size_t)b * DIM + d);
  else if (t >= 33 && t <= 2080)
    v = *(const float4*)(seg1 + ((size_t)b * SEQL + (t - 33)) * DIM + d);
  union { short s[4]; ull u; } o;
  o.s[0] = f2bf(v.x); o.s[1] = f2bf(v.y); o.s[2] = f2bf(v.z); o.s[3] = f2bf(v.w);
  *(ull*)(X + (size_t)b * Spad * DIM + lin) = o.u;
}

// ---------------------------------------------------------------------------
__global__ __launch_bounds__(256)
void mem_proj(const float* __restrict__ Sb, const float* __restrict__ M1,
              const float* __restrict__ Wq_mem, const float* __restrict__ bq_mem,
              const float* __restrict__ Wk_mem, const float* __restrict__ bk_mem,
              float* __restrict__ Qn, float* __restrict__ Kp)
{
  const int n = blockIdx.x * 256 + threadIdx.x;
  const int b = blockIdx.y;
  const int w = blockIdx.z;
  const float* x    = w ? M1 : Sb;
  const float* W    = w ? Wk_mem : Wq_mem;
  const float* bias = w ? bk_mem : bq_mem;
  float* o          = w ? Kp : Qn;
  const float* xr = x + (size_t)b * DIM;
  float s = bias[n];
  for (int k = 0; k < DIM; k++) s += xr[k] * W[(size_t)k * DIM + n];
  o[(size_t)b * DIM + n] = s;
}

__global__ __launch_bounds__(256)
void mem_attn(const float* __restrict__ Qn, const float* __restrict__ Kp,
              const float* __restrict__ M1, float* __restrict__ P1, float scale)
{
  __shared__ float red[256];
  __shared__ float w8[8];
  const int b = blockIdx.x, tid = threadIdx.x;
  for (int bp = 0; bp < NBATCH; bp++) {
    float p = 0.f;
    for (int k = tid; k < DIM; k += 256)
      p += Qn[(size_t)b * DIM + k] * Kp[(size_t)bp * DIM + k];
    red[tid] = p; __syncthreads();
    for (int off = 128; off; off >>= 1) {
      if (tid < off) red[tid] += red[tid + off];
      __syncthreads();
    }
    if (tid == 0) w8[bp] = red[0] * scale;
    __syncthreads();
  }
  if (tid == 0) {
    float m = w8[0];
    for (int i = 1; i < NBATCH; i++) m = fmaxf(m, w8[i]);
    float s = 0.f;
    for (int i = 0; i < NBATCH; i++) { w8[i] = __expf(w8[i] - m); s += w8[i]; }
    for (int i = 0; i < NBATCH; i++) w8[i] /= s;
  }
  __syncthreads();
  for (int d = tid; d < DIM; d += 256) {
    float a = 0.f;
    for (int bp = 0; bp < NBATCH; bp++) a += w8[bp] * M1[(size_t)bp * DIM + d];
    P1[(size_t)b * DIM + d] = a;
  }
}

// ---------------------------------------------------------------------------
extern "C" void kernel_launch(void* const* d_in, const int* in_sizes, int n_in,
                              void* d_out, int out_size, void* d_ws, size_t ws_size,
                              hipStream_t stream)
{
  const float* seg0   = (const float*)d_in[0];
  const float* seg1   = (const float*)d_in[1];
  const float* prompt = (const float*)d_in[2];
  const float* Wq_mem = (const float*)d_in[3];
  const float* bq_mem = (const float*)d_in[4];
  const float* Wk_mem = (const float*)d_in[5];
  const float* bk_mem = (const float*)d_in[6];
  const float* Wq     = (const float*)d_in[7];
  const float* bq     = (const float*)d_in[8];
  const float* Wk     = (const float*)d_in[9];
  const float* bk     = (const float*)d_in[10];
  const float* Wv     = (const float*)d_in[11];
  const float* bv     = (const float*)d_in[12];
  const float* Wo     = (const float*)d_in[13];
  const float* bo     = (const float*)d_in[14];
  float* outp = (float*)d_out;

  const size_t WSZ  = (size_t)DIM * DIM * 2;
  const size_t XSZ  = (size_t)NBATCH * SPMAX * DIM * 2;
  const size_t SASZ = (size_t)NBATCH * SPMAX * SPMAX * 2;
  const size_t VSZ  = (size_t)NBATCH * DIM * 4;

  char* p = (char*)d_ws;
  short* WqT = (short*)p; p += WSZ;
  short* WkT = (short*)p; p += WSZ;
  short* WvT = (short*)p; p += WSZ;
  short* WoT = (short*)p; p += WSZ;
  short* X   = (short*)p; p += XSZ;
  short* Qb  = (short*)p; p += XSZ;
  short* Kb  = (short*)p; p += XSZ;
  short* Vt  = (short*)p; p += XSZ;
  short* Ctx = (short*)p; p += XSZ;
  short* SA  = (short*)p; p += SASZ;
  float* M1b = (float*)p; p += VSZ;
  float* Sb  = (float*)p; p += VSZ;
  float* Qn  = (float*)p; p += VSZ;
  float* Kp  = (float*)p; p += VSZ;
  float* P1  = (float*)p; p += VSZ;

  const float scale = 0.03125f;   // 1/sqrt(1024)
  dim3 blk(256, 1, 1);
  dim3 blkG(512, 1, 1);

  auto run_backbone = [&](int Spad, int S,
                          float* o_dst, int t_lo, int t_hi, int outT,
                          float* o_sp, int t_sp) {
    const int MT = NBATCH * Spad / 256;   // 72 or 24
    // Q = X Wq^T + bq
    gemm_nt<1, 2><<<dim3(MT, DIM / 256, 1), blkG, 0, stream>>>(
        X, 0ULL, WqT, 0ULL, Qb, 0ULL, DIM, DIM, bq,
        nullptr, 0, 0, 0, nullptr, -1, Spad);
    // K = X Wk^T + bk
    gemm_nt<1, 2><<<dim3(MT, DIM / 256, 1), blkG, 0, stream>>>(
        X, 0ULL, WkT, 0ULL, Kb, 0ULL, DIM, DIM, bk,
        nullptr, 0, 0, 0, nullptr, -1, Spad);
    // Vt[b] (D x Spad) = NT(WvT, X_b) + bv[m]   (batch->XCD swizzle)
    gemm_nt<2, 1><<<dim3(Spad / 256, DIM / 256, NBATCH), blkG, 0, stream>>>(
        WvT, 0ULL, X, (ull)Spad * DIM,
        Vt, (ull)DIM * Spad, Spad, DIM, bv,
        nullptr, 0, 0, 0, nullptr, -1, Spad);
    // scores[b] = Q_b K_b^T   (batch->XCD swizzle)
    gemm_nt<0, 1><<<dim3(Spad / 256, Spad / 256, NBATCH), blkG, 0, stream>>>(
        Qb, (ull)Spad * DIM, Kb, (ull)Spad * DIM,
        SA, (ull)Spad * Spad, Spad, DIM, nullptr,
        nullptr, 0, 0, 0, nullptr, -1, Spad);
    softmax_rows<<<dim3(Spad, NBATCH), blk, 0, stream>>>(SA, Spad, S, scale);
    // ctx[b] = attn_b Vt_b^T   (batch->XCD swizzle)
    gemm_nt<0, 1><<<dim3(DIM / 256, Spad / 256, NBATCH), blkG, 0, stream>>>(
        SA, (ull)Spad * Spad, Vt, (ull)DIM * Spad,
        Ctx, (ull)Spad * DIM, DIM, Spad, nullptr,
        nullptr, 0, 0, 0, nullptr, -1, Spad);
    // H = ctx Wo^T + bo, scattered to outputs
    gemm_nt<3, 2><<<dim3(MT, DIM / 256, 1), blkG, 0, stream>>>(
        Ctx, 0ULL, WoT, 0ULL, nullptr, 0ULL, DIM, DIM, bo,
        o_dst, t_lo, t_hi, outT, o_sp, t_sp, Spad);
  };

  wtrans<<<dim3(32, 32), blk, 0, stream>>>(Wq, WqT);
  wtrans<<<dim3(32, 32), blk, 0, stream>>>(Wk, WkT);
  wtrans<<<dim3(32, 32), blk, 0, stream>>>(Wv, WvT);
  wtrans<<<dim3(32, 32), blk, 0, stream>>>(Wo, WoT);

  // Phase 0: backbone([P0, seg0, P0])  S=2050, Spad=2304
  assemble0<<<dim3(SPMAX, NBATCH), blk, 0, stream>>>(seg0, X);
  run_backbone(SPMAX, 2050, outp, 33, 2049, 2016, M1b, 2049);

  // Phase S: summarize(seg1)  S=514, Spad=768
  assembleS<<<dim3(768, NBATCH), blk, 0, stream>>>(seg1, prompt, X);
  run_backbone(768, 514, nullptr, 0, 0, 0, Sb, JSUM);

  // Memory attention (exact f32)
  mem_proj<<<dim3(DIM / 256, NBATCH, 2), blk, 0, stream>>>(
      Sb, M1b, Wq_mem, bq_mem, Wk_mem, bk_mem, Qn, Kp);
  mem_attn<<<dim3(NBATCH), blk, 0, stream>>>(Qn, Kp, M1b, P1, scale);

  // Phase 1: backbone([seg0[-32:], P1, seg1, P1])  S=2082, Spad=2304
  assemble1<<<dim3(SPMAX, NBATCH), blk, 0, stream>>>(seg0, seg1, P1, X);
  run_backbone(SPMAX, 2082, outp + (size_t)NBATCH * 2016 * DIM,
               33, 2081, 2048, nullptr, -1);
}

// Round 10
// 1552.209 us; speedup vs baseline: 1.2862x; 1.0945x over previous
//
#include <hip/hip_runtime.h>
#include <stdint.h>
#include <stddef.h>

#define DIM    1024
#define NBATCH 8
#define SEQL   2048
#define JSUM   512
#define SPMAX  2304

typedef unsigned long long ull;
typedef __attribute__((ext_vector_type(8))) __bf16 bf16x8;
typedef __attribute__((ext_vector_type(8))) short  short8;
typedef __attribute__((ext_vector_type(4))) float  floatx4;

__device__ __forceinline__ short f2bf(float f) {
  unsigned u = __builtin_bit_cast(unsigned, f);
  u = (u + 0x7fffu + ((u >> 16) & 1u)) >> 16;   // RNE
  return (short)u;
}
__device__ __forceinline__ float bf2f(short s) {
  unsigned u = ((unsigned)(unsigned short)s) << 16;
  return __builtin_bit_cast(float, u);
}

// NOTE: the intrinsic's imm-offset arg applies to BOTH global and LDS
// addresses — always pass 0 and do pointer arithmetic on both sides.
__device__ __forceinline__ void glds16(const short* g, short8* l) {
  __builtin_amdgcn_global_load_lds(
      (const __attribute__((address_space(1))) unsigned int*)g,
      (__attribute__((address_space(3))) unsigned int*)l, 16, 0, 0);
}

// Counted vmcnt wait (T4): never drain to 0 inside the K-loop.
#define VMCNT(n) do { asm volatile("s_waitcnt vmcnt(" #n ")" ::: "memory"); \
                      __builtin_amdgcn_sched_barrier(0); } while (0)

// Raw barrier WITHOUT the implicit s_waitcnt vmcnt(0) of __syncthreads().
__device__ __forceinline__ void barrier_raw() {
  asm volatile("" ::: "memory");
  __builtin_amdgcn_s_barrier();
  asm volatile("" ::: "memory");
}

// ---------------------------------------------------------------------------
// NT GEMM: C[m,n] = sum_k A[m,k]*B[n,k]. A rows stride ldA, B rows stride ldB
// (K-extent Kd decoupled from strides -> enables K-trim on zero-padded K).
//
// m201-template port (R9, verified): 256x256 tile, BK=64, 512 threads
// (8 waves, 2M x 4N, per-wave 128x64, acc[8][4] = 128 VGPR).
// LDS 128 KiB: 2 K-tile buffers x (A 32K + B 32K), fragment-major slot
// (k8,row) = k8*256 + row — conflict-free (measured 0, R0-R9),
// glds-linear-compatible (no swizzle needed).
//
// Per K-tile: 4 fine phases (ks x m-half), each:
//   { ds_read frags ; issue ONE 16KB half-tile stage (2 glds/thread) ;
//     barrier ; setprio(1) ; 16 MFMA ; setprio(0) ; [vmcnt guard] ; barrier }
// Stage units of tile t+1 issued in order A0,B0,A1,B1 during t's phases
// 0..3; consumed next tile in the SAME order. Guards:
//   p1-end vmcnt(4): A1,B1 of tile t landed for p2/p3.
//   p3-end vmcnt(4): A0',B0' landed for next tile's p0.
// vmcnt(0) only at the last tile's p1.  1 block/CU (VGPR: 256² forces
// acc=128/wave -> 2 waves/SIMD; LDS 128K). Known cost: grids of 288 pay
// a 2-round tail — addressed at the launch level (fused QK proj, K-trim).
// Requires M%256==0, N%256==0, K%64==0, K>=64.
// MODE 0: C bf16            MODE 1: C bf16 + bias[n]
// MODE 2: C bf16 + bias[m]  MODE 3: f32 scatter rows (+bias[n])
// SWIZ 1: gridDim.z==8; batch = lin&7 pins batch->XCD
// SWIZ 2: tm=blockIdx.x, tn=blockIdx.y, bz=0
// ---------------------------------------------------------------------------
template<int MODE, int SWIZ>
__global__ __launch_bounds__(512, 2)
void gemm_nt(const short* __restrict__ A, ull sA, int ldA,
             const short* __restrict__ Bm, ull sB, int ldB,
             short* __restrict__ Cb, ull sC,
             int N, int Kd,
             const float* __restrict__ bias,
             float* __restrict__ dst0, int t_lo, int t_hi, int outT,
             float* __restrict__ dstSp, int t_sp, int Spad)
{
  int tn, tm, bz;
  if (SWIZ == 1) {
    const unsigned gx = gridDim.x;
    ull lin = blockIdx.x + (ull)gx * (blockIdx.y + (ull)gridDim.y * blockIdx.z);
    bz = (int)(lin & 7);
    ull s = lin >> 3;
    tn = (int)(s % gx);
    tm = (int)(s / gx);
  } else {            // SWIZ == 2
    tm = blockIdx.x; tn = blockIdx.y; bz = 0;
  }

  A  += (ull)bz * sA;
  Bm += (ull)bz * sB;

  const int tid  = threadIdx.x;          // 0..511
  const int wave = tid >> 6, lane = tid & 63;

  __shared__ short8 ldsA[2][2048];   // 2 x 32 KB: slot = k8*256 + row, k8 0..7
  __shared__ short8 ldsB[2][2048];   // 2 x 32 KB

  // Staging thread map: slot s in {tid, tid+512} (+1024 for k-half 1):
  //   k8 = (s>>8) [+4h], row = s&255.  Dest = wave-uniform base + lane*16 OK.
  const int r0  = tid & 255;
  const int k80 = tid >> 8;                         // 0..1
  const short* pA = A  + (long long)(tm * 256 + r0) * ldA + k80 * 8;
  const short* pB = Bm + (long long)(tn * 256 + r0) * ldB + k80 * 8;

  floatx4 acc[8][4];
#pragma unroll
  for (int i = 0; i < 8; i++)
#pragma unroll
    for (int j = 0; j < 4; j++) acc[i][j] = (floatx4)(0.0f);

  const int wm = (wave >> 2) * 128;   // 2 M-halves of waves
  const int wn = (wave & 3) * 64;     // 4 N-quarters of waves
  const int fr = lane & 15;           // fragment row/col select
  const int fq = lane >> 4;           // k8 select (0..3) within a 32-K step

  const int nt = Kd >> 6;             // BK = 64

  // Prologue: stage tile 0's 4 units in guard order A0,B0,A1,B1.
  glds16(pA,      &ldsA[0][tid]);
  glds16(pA + 16, &ldsA[0][tid + 512]);
  glds16(pB,      &ldsB[0][tid]);
  glds16(pB + 16, &ldsB[0][tid + 512]);
  glds16(pA + 32, &ldsA[0][1024 + tid]);
  glds16(pA + 48, &ldsA[0][1024 + tid + 512]);
  glds16(pB + 32, &ldsB[0][1024 + tid]);
  glds16(pB + 48, &ldsB[0][1024 + tid + 512]);
  VMCNT(4);            // A0,B0 landed (A1,B1 still in flight)
  barrier_raw();

  for (int t = 0; t < nt; t++) {
    const short8* LA = ldsA[t & 1];
    const short8* LB = ldsB[t & 1];
    const int  nb   = (t + 1) & 1;
    const int  koff = (t + 1) * 64;
    const bool stg  = (t + 1) < nt;

    bf16x8 af[4], bv[4];

    // ---- phase 0: ks=0, m-half 0   (+stage A-half0 of t+1) ----
    {
      const int ka = fq * 256;
#pragma unroll
      for (int mt = 0; mt < 4; mt++)
        af[mt] = __builtin_bit_cast(bf16x8, LA[ka + wm + mt * 16 + fr]);
#pragma unroll
      for (int n2 = 0; n2 < 4; n2++)
        bv[n2] = __builtin_bit_cast(bf16x8, LB[ka + wn + n2 * 16 + fr]);
      if (stg) {
        glds16(pA + koff,      &ldsA[nb][tid]);
        glds16(pA + koff + 16, &ldsA[nb][tid + 512]);
      }
      barrier_raw();
      __builtin_amdgcn_s_setprio(1);
#pragma unroll
      for (int mt = 0; mt < 4; mt++)
#pragma unroll
        for (int n2 = 0; n2 < 4; n2++)
          acc[mt][n2] = __builtin_amdgcn_mfma_f32_16x16x32_bf16(
              af[mt], bv[n2], acc[mt][n2], 0, 0, 0);
      __builtin_amdgcn_s_setprio(0);
      barrier_raw();
    }

    // ---- phase 1: ks=0, m-half 1   (+stage B-half0) ----
    {
      const int ka = fq * 256;
#pragma unroll
      for (int mt = 0; mt < 4; mt++)
        af[mt] = __builtin_bit_cast(bf16x8, LA[ka + wm + 64 + mt * 16 + fr]);
      if (stg) {
        glds16(pB + koff,      &ldsB[nb][tid]);
        glds16(pB + koff + 16, &ldsB[nb][tid + 512]);
      }
      barrier_raw();
      __builtin_amdgcn_s_setprio(1);
#pragma unroll
      for (int mt = 0; mt < 4; mt++)
#pragma unroll
        for (int n2 = 0; n2 < 4; n2++)
          acc[4 + mt][n2] = __builtin_amdgcn_mfma_f32_16x16x32_bf16(
              af[mt], bv[n2], acc[4 + mt][n2], 0, 0, 0);
      __builtin_amdgcn_s_setprio(0);
      if (stg) VMCNT(4); else VMCNT(0);   // guard A1,B1 of tile t
      barrier_raw();
    }

    // ---- phase 2: ks=1, m-half 0   (+stage A-half1) ----
    {
      const int ka = (fq + 4) * 256;
#pragma unroll
      for (int mt = 0; mt < 4; mt++)
        af[mt] = __builtin_bit_cast(bf16x8, LA[ka + wm + mt * 16 + fr]);
#pragma unroll
      for (int n2 = 0; n2 < 4; n2++)
        bv[n2] = __builtin_bit_cast(bf16x8, LB[ka + wn + n2 * 16 + fr]);
      if (stg) {
        glds16(pA + koff + 32, &ldsA[nb][1024 + tid]);
        glds16(pA + koff + 48, &ldsA[nb][1024 + tid + 512]);
      }
      barrier_raw();
      __builtin_amdgcn_s_setprio(1);
#pragma unroll
      for (int mt = 0; mt < 4; mt++)
#pragma unroll
        for (int n2 = 0; n2 < 4; n2++)
          acc[mt][n2] = __builtin_amdgcn_mfma_f32_16x16x32_bf16(
              af[mt], bv[n2], acc[mt][n2], 0, 0, 0);
      __builtin_amdgcn_s_setprio(0);
      barrier_raw();
    }

    // ---- phase 3: ks=1, m-half 1   (+stage B-half1) ----
    {
      const int ka = (fq + 4) * 256;
#pragma unroll
      for (int mt = 0; mt < 4; mt++)
        af[mt] = __builtin_bit_cast(bf16x8, LA[ka + wm + 64 + mt * 16 + fr]);
      if (stg) {
        glds16(pB + koff + 32, &ldsB[nb][1024 + tid]);
        glds16(pB + koff + 48, &ldsB[nb][1024 + tid + 512]);
      }
      barrier_raw();
      __builtin_amdgcn_s_setprio(1);
#pragma unroll
      for (int mt = 0; mt < 4; mt++)
#pragma unroll
        for (int n2 = 0; n2 < 4; n2++)
          acc[4 + mt][n2] = __builtin_amdgcn_mfma_f32_16x16x32_bf16(
              af[mt], bv[n2], acc[4 + mt][n2], 0, 0, 0);
      __builtin_amdgcn_s_setprio(0);
      if (stg) VMCNT(4);                  // guard next tile's A0,B0
      barrier_raw();
    }
  }

  // Epilogue.  C/D layout: col = lane&15, row = (lane>>4)*4 + reg  [m89]
  // acc[mf][n2]: row-in-wave = (mf>>2)*64 + (mf&3)*16, col-in-wave = n2*16.
  if (MODE == 3) {
    // Tiles never straddle batches (Spad % 256 == 0): derive batch once.
    const int bb  = (tm * 256) / Spad;
    const int rb0 = tm * 256 - bb * Spad + wm + fq * 4;
#pragma unroll
    for (int mf = 0; mf < 8; mf++) {
#pragma unroll
      for (int n2 = 0; n2 < 4; n2++) {
        const int col = tn * 256 + wn + n2 * 16 + fr;
#pragma unroll
        for (int r = 0; r < 4; r++) {
          const int tt = rb0 + (mf >> 2) * 64 + (mf & 3) * 16 + r;
          float v = acc[mf][n2][r] + bias[col];
          if (tt >= t_lo && tt < t_hi)
            dst0[((size_t)bb * outT + (tt - t_lo)) * DIM + col] = v;
          else if (tt == t_sp)
            dstSp[(size_t)bb * DIM + col] = v;
        }
      }
    }
  } else {
    short* C = Cb + (ull)bz * sC;
#pragma unroll
    for (int mf = 0; mf < 8; mf++) {
#pragma unroll
      for (int n2 = 0; n2 < 4; n2++) {
        const int col = tn * 256 + wn + n2 * 16 + fr;
        float bn = (MODE == 1) ? bias[col] : 0.0f;
#pragma unroll
        for (int r = 0; r < 4; r++) {
          const int row = tm * 256 + wm + (mf >> 2) * 64 + (mf & 3) * 16 + fq * 4 + r;
          float v = acc[mf][n2][r] + bn;
          if (MODE == 2) v += bias[row];
          C[(size_t)row * N + col] = f2bf(v);
        }
      }
    }
  }
}

// ---------------------------------------------------------------------------
// In-place row softmax over bf16 score rows. Row length Spad, valid k < S.
// Vectorized short8 load/store (G13).
// ---------------------------------------------------------------------------
__global__ __launch_bounds__(256)
void softmax_rows(short* __restrict__ SA, int Spad, int S, float scale)
{
  __shared__ float buf[SPMAX];
  __shared__ float red[8];
  const int t = blockIdx.x, b = blockIdx.y;
  short* row = SA + ((size_t)b * Spad + t) * Spad;
  const int tid = threadIdx.x;
  const int nv = S >> 3;                  // full short8 groups

  float mx = -1e30f;
  for (int g = tid; g < nv; g += 256) {
    short8 v = ((const short8*)row)[g];
#pragma unroll
    for (int j = 0; j < 8; j++) {
      float f = bf2f(v[j]) * scale;
      buf[g * 8 + j] = f;
      mx = fmaxf(mx, f);
    }
  }
  for (int i = (nv << 3) + tid; i < S; i += 256) {
    float f = bf2f(row[i]) * scale;
    buf[i] = f;
    mx = fmaxf(mx, f);
  }
  for (int off = 32; off; off >>= 1) mx = fmaxf(mx, __shfl_down(mx, off, 64));
  if ((tid & 63) == 0) red[tid >> 6] = mx;
  __syncthreads();
  if (tid == 0) {
    float m = red[0];
    for (int w = 1; w < 4; w++) m = fmaxf(m, red[w]);
    red[0] = m;
  }
  __syncthreads();
  mx = red[0];

  float sum = 0.f;
  for (int i = tid; i < S; i += 256) {
    float e = __expf(buf[i] - mx);
    buf[i] = e;
    sum += e;
  }
  for (int off = 32; off; off >>= 1) sum += __shfl_down(sum, off, 64);
  if ((tid & 63) == 0) red[4 + (tid >> 6)] = sum;
  __syncthreads();
  if (tid == 0) red[4] = 1.0f / (red[4] + red[5] + red[6] + red[7]);
  __syncthreads();
  const float rinv = red[4];

  for (int g = tid; g < nv; g += 256) {
    short8 o;
#pragma unroll
    for (int j = 0; j < 8; j++) o[j] = f2bf(buf[g * 8 + j] * rinv);
    ((short8*)row)[g] = o;
  }
  for (int i = (nv << 3) + tid; i < S; i += 256) row[i] = f2bf(buf[i] * rinv);
  for (int i = S + tid; i < Spad; i += 256) row[i] = 0;
}

// ---------------------------------------------------------------------------
__global__ __launch_bounds__(256)
void wtrans(const float* __restrict__ W, short* __restrict__ WT)
{
  __shared__ float tile[32][33];
  const int bn = blockIdx.x * 32, bk = blockIdx.y * 32;
  const int tx = threadIdx.x & 31, ty = threadIdx.x >> 5;  // 32 x 8
#pragma unroll
  for (int j = 0; j < 4; j++)
    tile[ty + j * 8][tx] = W[(size_t)(bk + ty + j * 8) * DIM + bn + tx];
  __syncthreads();
#pragma unroll
  for (int j = 0; j < 4; j++)
    WT[(size_t)(bn + ty + j * 8) * DIM + bk + tx] = f2bf(tile[tx][ty + j * 8]);
}

// Concat bq|bk into one 2048-float bias for the fused QK projection.
__global__ __launch_bounds__(256)
void bcat(const float* __restrict__ a, const float* __restrict__ b,
          float* __restrict__ o)
{
  const int i = blockIdx.x * 256 + threadIdx.x;
  o[i] = (i < DIM) ? a[i] : b[i - DIM];
}

// ---------------------------------------------------------------------------
__global__ __launch_bounds__(256)
void assemble0(const float* __restrict__ seg0, short* __restrict__ X)
{
  const int Spad = SPMAX;
  const int b = blockIdx.y;
  const size_t lin = ((size_t)blockIdx.x * 256 + threadIdx.x) * 4;
  const int t = (int)(lin >> 10), d = (int)(lin & 1023);
  float4 v = make_float4(0.f, 0.f, 0.f, 0.f);
  if (t >= 1 && t <= SEQL)
    v = *(const float4*)(seg0 + ((size_t)b * SEQL + (t - 1)) * DIM + d);
  union { short s[4]; ull u; } o;
  o.s[0] = f2bf(v.x); o.s[1] = f2bf(v.y); o.s[2] = f2bf(v.z); o.s[3] = f2bf(v.w);
  *(ull*)(X + (size_t)b * Spad * DIM + lin) = o.u;
}

__global__ __launch_bounds__(256)
void assembleS(const float* __restrict__ seg1, const float* __restrict__ prompt,
               short* __restrict__ X)
{
  const int Spad = 768;
  const int b = blockIdx.y;
  const size_t lin = ((size_t)blockIdx.x * 256 + threadIdx.x) * 4;
  const int t = (int)(lin >> 10), d = (int)(lin & 1023);
  float4 v = make_float4(0.f, 0.f, 0.f, 0.f);
  if (t == 0 || t == JSUM + 1)
    v = *(const float4*)(prompt + d);
  else if (t >= 1 && t <= JSUM)
    v = *(const float4*)(seg1 + ((size_t)b * SEQL + (t - 1)) * DIM + d);
  union { short s[4]; ull u; } o;
  o.s[0] = f2bf(v.x); o.s[1] = f2bf(v.y); o.s[2] = f2bf(v.z); o.s[3] = f2bf(v.w);
  *(ull*)(X + (size_t)b * Spad * DIM + lin) = o.u;
}

__global__ __launch_bounds__(256)
void assemble1(const float* __restrict__ seg0, const float* __restrict__ seg1,
               const float* __restrict__ P1, short* __restrict__ X)
{
  const int Spad = SPMAX;
  const int b = blockIdx.y;
  const size_t lin = ((size_t)blockIdx.x * 256 + threadIdx.x) * 4;
  const int t = (int)(lin >> 10), d = (int)(lin & 1023);
  float4 v = make_float4(0.f, 0.f, 0.f, 0.f);
  if (t < 32)
    v = *(const float4*)(seg0 + ((size_t)b * SEQL + (SEQL - 32 + t)) * DIM + d);
  else if (t == 32 || t == 2081)
    v = *(const float4*)(P1 + (size_t)b * DIM + d);
  else if (t >= 33 && t <= 2080)
    v = *(const float4*)(seg1 + ((size_t)b * SEQL + (t - 33)) * DIM + d);
  union { short s[4]; ull u; } o;
  o.s[0] = f2bf(v.x); o.s[1] = f2bf(v.y); o.s[2] = f2bf(v.z); o.s[3] = f2bf(v.w);
  *(ull*)(X + (size_t)b * Spad * DIM + lin) = o.u;
}

// ---------------------------------------------------------------------------
__global__ __launch_bounds__(256)
void mem_proj(const float* __restrict__ Sb, const float* __restrict__ M1,
              const float* __restrict__ Wq_mem, const float* __restrict__ bq_mem,
              const float* __restrict__ Wk_mem, const float* __restrict__ bk_mem,
              float* __restrict__ Qn, float* __restrict__ Kp)
{
  const int n = blockIdx.x * 256 + threadIdx.x;
  const int b = blockIdx.y;
  const int w = blockIdx.z;
  const float* x    = w ? M1 : Sb;
  const float* W    = w ? Wk_mem : Wq_mem;
  const float* bias = w ? bk_mem : bq_mem;
  float* o          = w ? Kp : Qn;
  const float* xr = x + (size_t)b * DIM;
  float s = bias[n];
  for (int k = 0; k < DIM; k++) s += xr[k] * W[(size_t)k * DIM + n];
  o[(size_t)b * DIM + n] = s;
}

__global__ __launch_bounds__(256)
void mem_attn(const float* __restrict__ Qn, const float* __restrict__ Kp,
              const float* __restrict__ M1, float* __restrict__ P1, float scale)
{
  __shared__ float red[256];
  __shared__ float w8[8];
  const int b = blockIdx.x, tid = threadIdx.x;
  for (int bp = 0; bp < NBATCH; bp++) {
    float p = 0.f;
    for (int k = tid; k < DIM; k += 256)
      p += Qn[(size_t)b * DIM + k] * Kp[(size_t)bp * DIM + k];
    red[tid] = p; __syncthreads();
    for (int off = 128; off; off >>= 1) {
      if (tid < off) red[tid] += red[tid + off];
      __syncthreads();
    }
    if (tid == 0) w8[bp] = red[0] * scale;
    __syncthreads();
  }
  if (tid == 0) {
    float m = w8[0];
    for (int i = 1; i < NBATCH; i++) m = fmaxf(m, w8[i]);
    float s = 0.f;
    for (int i = 0; i < NBATCH; i++) { w8[i] = __expf(w8[i] - m); s += w8[i]; }
    for (int i = 0; i < NBATCH; i++) w8[i] /= s;
  }
  __syncthreads();
  for (int d = tid; d < DIM; d += 256) {
    float a = 0.f;
    for (int bp = 0; bp < NBATCH; bp++) a += w8[bp] * M1[(size_t)bp * DIM + d];
    P1[(size_t)b * DIM + d] = a;
  }
}

// ---------------------------------------------------------------------------
extern "C" void kernel_launch(void* const* d_in, const int* in_sizes, int n_in,
                              void* d_out, int out_size, void* d_ws, size_t ws_size,
                              hipStream_t stream)
{
  const float* seg0   = (const float*)d_in[0];
  const float* seg1   = (const float*)d_in[1];
  const float* prompt = (const float*)d_in[2];
  const float* Wq_mem = (const float*)d_in[3];
  const float* bq_mem = (const float*)d_in[4];
  const float* Wk_mem = (const float*)d_in[5];
  const float* bk_mem = (const float*)d_in[6];
  const float* Wq     = (const float*)d_in[7];
  const float* bq     = (const float*)d_in[8];
  const float* Wk     = (const float*)d_in[9];
  const float* bk     = (const float*)d_in[10];
  const float* Wv     = (const float*)d_in[11];
  const float* bv     = (const float*)d_in[12];
  const float* Wo     = (const float*)d_in[13];
  const float* bo     = (const float*)d_in[14];
  float* outp = (float*)d_out;

  const size_t WSZ  = (size_t)DIM * DIM * 2;
  const size_t XSZ  = (size_t)NBATCH * SPMAX * DIM * 2;
  const size_t SASZ = (size_t)NBATCH * SPMAX * SPMAX * 2;
  const size_t VSZ  = (size_t)NBATCH * DIM * 4;

  char* p = (char*)d_ws;
  short* WqT = (short*)p; p += WSZ;     // WqT and WkT contiguous -> WqkT
  short* WkT = (short*)p; p += WSZ;
  short* WvT = (short*)p; p += WSZ;
  short* WoT = (short*)p; p += WSZ;
  short* X   = (short*)p; p += XSZ;
  short* QKb = (short*)p; p += 2 * XSZ;  // fused Q|K output, row stride 2048
  short* Vt  = (short*)p; p += XSZ;
  short* Ctx = (short*)p; p += XSZ;
  short* SA  = (short*)p; p += SASZ;
  float* M1b = (float*)p; p += VSZ;
  float* Sb  = (float*)p; p += VSZ;
  float* Qn  = (float*)p; p += VSZ;
  float* Kp  = (float*)p; p += VSZ;
  float* P1  = (float*)p; p += VSZ;
  float* bqk = (float*)p; p += 2 * DIM * 4;

  const float scale = 0.03125f;   // 1/sqrt(1024)
  dim3 blk(256, 1, 1);
  dim3 blkG(512, 1, 1);

  auto run_backbone = [&](int Spad, int S, int kAV,
                          float* o_dst, int t_lo, int t_hi, int outT,
                          float* o_sp, int t_sp) {
    const int MT = NBATCH * Spad / 256;   // 72 or 24
    // Fused [Q|K] = X [Wq|Wk]^T + [bq|bk]  (N=2048, one pass over X)
    gemm_nt<1, 2><<<dim3(MT, 2048 / 256, 1), blkG, 0, stream>>>(
        X, 0ULL, DIM, WqT, 0ULL, DIM, QKb, 0ULL, 2048, DIM, bqk,
        nullptr, 0, 0, 0, nullptr, -1, Spad);
    // Vt[b] (D x Spad) = NT(WvT, X_b) + bv[m]   (batch->XCD swizzle)
    gemm_nt<2, 1><<<dim3(Spad / 256, DIM / 256, NBATCH), blkG, 0, stream>>>(
        WvT, 0ULL, DIM, X, (ull)Spad * DIM, DIM,
        Vt, (ull)DIM * Spad, Spad, DIM, bv,
        nullptr, 0, 0, 0, nullptr, -1, Spad);
    // scores[b] = Q_b K_b^T   (Q,K strided ld=2048 inside QKb)
    gemm_nt<0, 1><<<dim3(Spad / 256, Spad / 256, NBATCH), blkG, 0, stream>>>(
        QKb, (ull)Spad * 2048, 2048, QKb + DIM, (ull)Spad * 2048, 2048,
        SA, (ull)Spad * Spad, Spad, DIM, nullptr,
        nullptr, 0, 0, 0, nullptr, -1, Spad);
    softmax_rows<<<dim3(Spad, NBATCH), blk, 0, stream>>>(SA, Spad, S, scale);
    // ctx[b] = attn_b Vt_b^T   — K-trimmed to kAV (SA cols >= S are zeroed
    // by softmax; Vt cols >= S are finite bias values -> exact).
    gemm_nt<0, 1><<<dim3(DIM / 256, Spad / 256, NBATCH), blkG, 0, stream>>>(
        SA, (ull)Spad * Spad, Spad, Vt, (ull)DIM * Spad, Spad,
        Ctx, (ull)Spad * DIM, DIM, kAV, nullptr,
        nullptr, 0, 0, 0, nullptr, -1, Spad);
    // H = ctx Wo^T + bo, scattered to outputs
    gemm_nt<3, 2><<<dim3(MT, DIM / 256, 1), blkG, 0, stream>>>(
        Ctx, 0ULL, DIM, WoT, 0ULL, DIM, nullptr, 0ULL, DIM, DIM, bo,
        o_dst, t_lo, t_hi, outT, o_sp, t_sp, Spad);
  };

  wtrans<<<dim3(32, 32), blk, 0, stream>>>(Wq, WqT);
  wtrans<<<dim3(32, 32), blk, 0, stream>>>(Wk, WkT);
  wtrans<<<dim3(32, 32), blk, 0, stream>>>(Wv, WvT);
  wtrans<<<dim3(32, 32), blk, 0, stream>>>(Wo, WoT);
  bcat<<<dim3(8), blk, 0, stream>>>(bq, bk, bqk);

  // Phase 0: backbone([P0, seg0, P0])  S=2050, Spad=2304, kAV=2112 (33x64>=2050)
  assemble0<<<dim3(SPMAX, NBATCH), blk, 0, stream>>>(seg0, X);
  run_backbone(SPMAX, 2050, 2112, outp, 33, 2049, 2016, M1b, 2049);

  // Phase S: summarize(seg1)  S=514, Spad=768, kAV=576 (9x64>=514)
  assembleS<<<dim3(768, NBATCH), blk, 0, stream>>>(seg1, prompt, X);
  run_backbone(768, 514, 576, nullptr, 0, 0, 0, Sb, JSUM);

  // Memory attention (exact f32)
  mem_proj<<<dim3(DIM / 256, NBATCH, 2), blk, 0, stream>>>(
      Sb, M1b, Wq_mem, bq_mem, Wk_mem, bk_mem, Qn, Kp);
  mem_attn<<<dim3(NBATCH), blk, 0, stream>>>(Qn, Kp, M1b, P1, scale);

  // Phase 1: backbone([seg0[-32:], P1, seg1, P1])  S=2082, Spad=2304, kAV=2112
  assemble1<<<dim3(SPMAX, NBATCH), blk, 0, stream>>>(seg0, seg1, P1, X);
  run_backbone(SPMAX, 2082, 2112, outp + (size_t)NBATCH * 2016 * DIM,
               33, 2081, 2048, nullptr, -1);
}

// Round 11
// 1441.934 us; speedup vs baseline: 1.3846x; 1.0765x over previous
//
#include <hip/hip_runtime.h>
#include <stdint.h>
#include <stddef.h>

#define DIM    1024
#define NBATCH 8
#define SEQL   2048
#define JSUM   512
#define SPMAX  2304
#define SPS    768

typedef unsigned long long ull;
typedef __attribute__((ext_vector_type(8))) __bf16 bf16x8;
typedef __attribute__((ext_vector_type(8))) short  short8;
typedef __attribute__((ext_vector_type(4))) float  floatx4;

__device__ __forceinline__ short f2bf(float f) {
  unsigned u = __builtin_bit_cast(unsigned, f);
  u = (u + 0x7fffu + ((u >> 16) & 1u)) >> 16;   // RNE
  return (short)u;
}
__device__ __forceinline__ float bf2f(short s) {
  unsigned u = ((unsigned)(unsigned short)s) << 16;
  return __builtin_bit_cast(float, u);
}

// NOTE: the intrinsic's imm-offset arg applies to BOTH global and LDS
// addresses — always pass 0 and do pointer arithmetic on both sides.
__device__ __forceinline__ void glds16(const short* g, short8* l) {
  __builtin_amdgcn_global_load_lds(
      (const __attribute__((address_space(1))) unsigned int*)g,
      (__attribute__((address_space(3))) unsigned int*)l, 16, 0, 0);
}

// Counted vmcnt wait (T4): never drain to 0 inside the K-loop.
#define VMCNT(n) do { asm volatile("s_waitcnt vmcnt(" #n ")" ::: "memory"); \
                      __builtin_amdgcn_sched_barrier(0); } while (0)

// Raw barrier WITHOUT the implicit s_waitcnt vmcnt(0) of __syncthreads().
__device__ __forceinline__ void barrier_raw() {
  asm volatile("" ::: "memory");
  __builtin_amdgcn_s_barrier();
  asm volatile("" ::: "memory");
}

// ---------------------------------------------------------------------------
// Two-problem GEMM parameter block. A dispatch carries TWO independent
// NT-GEMM problems (R10 post-mortem: makespan = ceil(blocks/256)*T at
// 1 blk/CU; phase-S's small grids pack into phase-0's tail rounds).
// Blocks with pid < q0.nblk run q0, the rest q1. For single-problem
// launches pass the same struct twice with nblk = grid size.
// ---------------------------------------------------------------------------
struct GemmP {
  const short* A; ull sA; int ldA;
  const short* B; ull sB; int ldB;
  short* C; ull sC;
  int N, Kd;
  const float* bias;
  float* dst0; int t_lo, t_hi, outT;
  float* dstSp; int t_sp, Spad;
  int gx;      // N-tiles (SWIZ1) or M-tiles (SWIZ2) for decode
  int nblk;    // total blocks of this problem
};

// ---------------------------------------------------------------------------
// NT GEMM: C[m,n] = sum_k A[m,k]*B[n,k]. Row strides ldA/ldB decoupled from
// Kd (K-trim on zero-padded K).
// m201-template (R9/R10, verified): 256x256 tile, BK=64, 512 threads
// (8 waves, 2M x 4N, per-wave 128x64, acc[8][4] = 128 VGPR).
// LDS 128 KiB: 2 K-tile buffers x (A 32K + B 32K), fragment-major slot
// (k8,row) = k8*256 + row — conflict-free (measured 0, R0-R10),
// glds-linear-compatible.
// Per K-tile: 4 fine phases (ks x m-half), each:
//   { ds_read frags ; issue ONE 16KB half-tile stage (2 glds/thread) ;
//     barrier ; setprio(1) ; 16 MFMA ; setprio(0) ; [vmcnt guard] ; barrier }
// Stage units of tile t+1 issued A0,B0,A1,B1 during t's phases 0..3;
// consumed next tile in the same order. Guards: p1-end vmcnt(4) (A1,B1 of
// t landed), p3-end vmcnt(4) (A0',B0' landed). vmcnt(0) only at last tile.
// MODE 0: C bf16            MODE 1: C bf16 + bias[n]
// MODE 2: C bf16 + bias[m]  MODE 3: f32 scatter rows (+bias[n])
// SWIZ 1: batch = lid&7 pins batch->XCD; tn = (lid>>3)%gx, tm = /gx
// SWIZ 2: tm = lid%gx, tn = lid/gx, bz=0
// ---------------------------------------------------------------------------
template<int MODE, int SWIZ>
__global__ __launch_bounds__(512, 2)
void gemm_nt(GemmP q0, GemmP q1)
{
  const int  pid = blockIdx.x;
  const bool s1  = pid >= q0.nblk;
  const GemmP& q = s1 ? q1 : q0;
  const int  lid = s1 ? (pid - q0.nblk) : pid;

  int tn, tm, bz;
  if (SWIZ == 1) {
    bz = lid & 7;
    const int s = lid >> 3;
    tn = s % q.gx;
    tm = s / q.gx;
  } else {            // SWIZ == 2
    tm = lid % q.gx;
    tn = lid / q.gx;
    bz = 0;
  }

  const short* A  = q.A + (ull)bz * q.sA;
  const short* Bm = q.B + (ull)bz * q.sB;

  const int tid  = threadIdx.x;          // 0..511
  const int wave = tid >> 6, lane = tid & 63;

  __shared__ short8 ldsA[2][2048];   // 2 x 32 KB: slot = k8*256 + row, k8 0..7
  __shared__ short8 ldsB[2][2048];   // 2 x 32 KB

  const int r0  = tid & 255;
  const int k80 = tid >> 8;                         // 0..1
  const short* pA = A  + (long long)(tm * 256 + r0) * q.ldA + k80 * 8;
  const short* pB = Bm + (long long)(tn * 256 + r0) * q.ldB + k80 * 8;

  floatx4 acc[8][4];
#pragma unroll
  for (int i = 0; i < 8; i++)
#pragma unroll
    for (int j = 0; j < 4; j++) acc[i][j] = (floatx4)(0.0f);

  const int wm = (wave >> 2) * 128;   // 2 M-halves of waves
  const int wn = (wave & 3) * 64;     // 4 N-quarters of waves
  const int fr = lane & 15;           // fragment row/col select
  const int fq = lane >> 4;           // k8 select (0..3) within a 32-K step

  const int nt = q.Kd >> 6;           // BK = 64

  // Prologue: stage tile 0's 4 units in guard order A0,B0,A1,B1.
  glds16(pA,      &ldsA[0][tid]);
  glds16(pA + 16, &ldsA[0][tid + 512]);
  glds16(pB,      &ldsB[0][tid]);
  glds16(pB + 16, &ldsB[0][tid + 512]);
  glds16(pA + 32, &ldsA[0][1024 + tid]);
  glds16(pA + 48, &ldsA[0][1024 + tid + 512]);
  glds16(pB + 32, &ldsB[0][1024 + tid]);
  glds16(pB + 48, &ldsB[0][1024 + tid + 512]);
  VMCNT(4);            // A0,B0 landed (A1,B1 still in flight)
  barrier_raw();

  for (int t = 0; t < nt; t++) {
    const short8* LA = ldsA[t & 1];
    const short8* LB = ldsB[t & 1];
    const int  nb   = (t + 1) & 1;
    const int  koff = (t + 1) * 64;
    const bool stg  = (t + 1) < nt;

    bf16x8 af[4], bv[4];

    // ---- phase 0: ks=0, m-half 0   (+stage A-half0 of t+1) ----
    {
      const int ka = fq * 256;
#pragma unroll
      for (int mt = 0; mt < 4; mt++)
        af[mt] = __builtin_bit_cast(bf16x8, LA[ka + wm + mt * 16 + fr]);
#pragma unroll
      for (int n2 = 0; n2 < 4; n2++)
        bv[n2] = __builtin_bit_cast(bf16x8, LB[ka + wn + n2 * 16 + fr]);
      if (stg) {
        glds16(pA + koff,      &ldsA[nb][tid]);
        glds16(pA + koff + 16, &ldsA[nb][tid + 512]);
      }
      barrier_raw();
      __builtin_amdgcn_s_setprio(1);
#pragma unroll
      for (int mt = 0; mt < 4; mt++)
#pragma unroll
        for (int n2 = 0; n2 < 4; n2++)
          acc[mt][n2] = __builtin_amdgcn_mfma_f32_16x16x32_bf16(
              af[mt], bv[n2], acc[mt][n2], 0, 0, 0);
      __builtin_amdgcn_s_setprio(0);
      barrier_raw();
    }

    // ---- phase 1: ks=0, m-half 1   (+stage B-half0) ----
    {
      const int ka = fq * 256;
#pragma unroll
      for (int mt = 0; mt < 4; mt++)
        af[mt] = __builtin_bit_cast(bf16x8, LA[ka + wm + 64 + mt * 16 + fr]);
      if (stg) {
        glds16(pB + koff,      &ldsB[nb][tid]);
        glds16(pB + koff + 16, &ldsB[nb][tid + 512]);
      }
      barrier_raw();
      __builtin_amdgcn_s_setprio(1);
#pragma unroll
      for (int mt = 0; mt < 4; mt++)
#pragma unroll
        for (int n2 = 0; n2 < 4; n2++)
          acc[4 + mt][n2] = __builtin_amdgcn_mfma_f32_16x16x32_bf16(
              af[mt], bv[n2], acc[4 + mt][n2], 0, 0, 0);
      __builtin_amdgcn_s_setprio(0);
      if (stg) VMCNT(4); else VMCNT(0);   // guard A1,B1 of tile t
      barrier_raw();
    }

    // ---- phase 2: ks=1, m-half 0   (+stage A-half1) ----
    {
      const int ka = (fq + 4) * 256;
#pragma unroll
      for (int mt = 0; mt < 4; mt++)
        af[mt] = __builtin_bit_cast(bf16x8, LA[ka + wm + mt * 16 + fr]);
#pragma unroll
      for (int n2 = 0; n2 < 4; n2++)
        bv[n2] = __builtin_bit_cast(bf16x8, LB[ka + wn + n2 * 16 + fr]);
      if (stg) {
        glds16(pA + koff + 32, &ldsA[nb][1024 + tid]);
        glds16(pA + koff + 48, &ldsA[nb][1024 + tid + 512]);
      }
      barrier_raw();
      __builtin_amdgcn_s_setprio(1);
#pragma unroll
      for (int mt = 0; mt < 4; mt++)
#pragma unroll
        for (int n2 = 0; n2 < 4; n2++)
          acc[mt][n2] = __builtin_amdgcn_mfma_f32_16x16x32_bf16(
              af[mt], bv[n2], acc[mt][n2], 0, 0, 0);
      __builtin_amdgcn_s_setprio(0);
      barrier_raw();
    }

    // ---- phase 3: ks=1, m-half 1   (+stage B-half1) ----
    {
      const int ka = (fq + 4) * 256;
#pragma unroll
      for (int mt = 0; mt < 4; mt++)
        af[mt] = __builtin_bit_cast(bf16x8, LA[ka + wm + 64 + mt * 16 + fr]);
      if (stg) {
        glds16(pB + koff + 32, &ldsB[nb][1024 + tid]);
        glds16(pB + koff + 48, &ldsB[nb][1024 + tid + 512]);
      }
      barrier_raw();
      __builtin_amdgcn_s_setprio(1);
#pragma unroll
      for (int mt = 0; mt < 4; mt++)
#pragma unroll
        for (int n2 = 0; n2 < 4; n2++)
          acc[4 + mt][n2] = __builtin_amdgcn_mfma_f32_16x16x32_bf16(
              af[mt], bv[n2], acc[4 + mt][n2], 0, 0, 0);
      __builtin_amdgcn_s_setprio(0);
      if (stg) VMCNT(4);                  // guard next tile's A0,B0
      barrier_raw();
    }
  }

  // Epilogue.  C/D layout: col = lane&15, row = (lane>>4)*4 + reg  [m89]
  // acc[mf][n2]: row-in-wave = (mf>>2)*64 + (mf&3)*16, col-in-wave = n2*16.
  if (MODE == 3) {
    // Tiles never straddle batches (Spad % 256 == 0): derive batch once.
    const int bb  = (tm * 256) / q.Spad;
    const int rb0 = tm * 256 - bb * q.Spad + wm + fq * 4;
#pragma unroll
    for (int mf = 0; mf < 8; mf++) {
#pragma unroll
      for (int n2 = 0; n2 < 4; n2++) {
        const int col = tn * 256 + wn + n2 * 16 + fr;
#pragma unroll
        for (int r = 0; r < 4; r++) {
          const int tt = rb0 + (mf >> 2) * 64 + (mf & 3) * 16 + r;
          float v = acc[mf][n2][r] + q.bias[col];
          if (tt >= q.t_lo && tt < q.t_hi)
            q.dst0[((size_t)bb * q.outT + (tt - q.t_lo)) * DIM + col] = v;
          else if (tt == q.t_sp)
            q.dstSp[(size_t)bb * DIM + col] = v;
        }
      }
    }
  } else {
    short* C = q.C + (ull)bz * q.sC;
#pragma unroll
    for (int mf = 0; mf < 8; mf++) {
#pragma unroll
      for (int n2 = 0; n2 < 4; n2++) {
        const int col = tn * 256 + wn + n2 * 16 + fr;
        float bn = (MODE == 1) ? q.bias[col] : 0.0f;
#pragma unroll
        for (int r = 0; r < 4; r++) {
          const int row = tm * 256 + wm + (mf >> 2) * 64 + (mf & 3) * 16 + fq * 4 + r;
          float v = acc[mf][n2][r] + bn;
          if (MODE == 2) v += q.bias[row];
          C[(size_t)row * q.N + col] = f2bf(v);
        }
      }
    }
  }
}

// ---------------------------------------------------------------------------
// Merged two-problem row softmax (bf16 rows, in place). Rows t < nx0 belong
// to problem 0 (SA0, Spad0, S0); the rest to problem 1. Vectorized short8.
// ---------------------------------------------------------------------------
__global__ __launch_bounds__(256)
void softmax_rows2(short* __restrict__ SA0, int Spad0, int S0, int nx0,
                   short* __restrict__ SA1, int Spad1, int S1, float scale)
{
  __shared__ float buf[SPMAX];
  __shared__ float red[8];
  int t = blockIdx.x;
  const int b = blockIdx.y;
  short* row; int Spad, S;
  if (t < nx0) { row = SA0 + ((size_t)b * Spad0 + t) * Spad0; Spad = Spad0; S = S0; }
  else { t -= nx0; row = SA1 + ((size_t)b * Spad1 + t) * Spad1; Spad = Spad1; S = S1; }
  const int tid = threadIdx.x;
  const int nv = S >> 3;

  float mx = -1e30f;
  for (int g = tid; g < nv; g += 256) {
    short8 v = ((const short8*)row)[g];
#pragma unroll
    for (int j = 0; j < 8; j++) {
      float f = bf2f(v[j]) * scale;
      buf[g * 8 + j] = f;
      mx = fmaxf(mx, f);
    }
  }
  for (int i = (nv << 3) + tid; i < S; i += 256) {
    float f = bf2f(row[i]) * scale;
    buf[i] = f;
    mx = fmaxf(mx, f);
  }
  for (int off = 32; off; off >>= 1) mx = fmaxf(mx, __shfl_down(mx, off, 64));
  if ((tid & 63) == 0) red[tid >> 6] = mx;
  __syncthreads();
  if (tid == 0) {
    float m = red[0];
    for (int w = 1; w < 4; w++) m = fmaxf(m, red[w]);
    red[0] = m;
  }
  __syncthreads();
  mx = red[0];

  float sum = 0.f;
  for (int i = tid; i < S; i += 256) {
    float e = __expf(buf[i] - mx);
    buf[i] = e;
    sum += e;
  }
  for (int off = 32; off; off >>= 1) sum += __shfl_down(sum, off, 64);
  if ((tid & 63) == 0) red[4 + (tid >> 6)] = sum;
  __syncthreads();
  if (tid == 0) red[4] = 1.0f / (red[4] + red[5] + red[6] + red[7]);
  __syncthreads();
  const float rinv = red[4];

  for (int g = tid; g < nv; g += 256) {
    short8 o;
#pragma unroll
    for (int j = 0; j < 8; j++) o[j] = f2bf(buf[g * 8 + j] * rinv);
    ((short8*)row)[g] = o;
  }
  for (int i = (nv << 3) + tid; i < S; i += 256) row[i] = f2bf(buf[i] * rinv);
  for (int i = S + tid; i < Spad; i += 256) row[i] = 0;
}

// ---------------------------------------------------------------------------
__global__ __launch_bounds__(256)
void wtrans(const float* __restrict__ W, short* __restrict__ WT)
{
  __shared__ float tile[32][33];
  const int bn = blockIdx.x * 32, bk = blockIdx.y * 32;
  const int tx = threadIdx.x & 31, ty = threadIdx.x >> 5;  // 32 x 8
#pragma unroll
  for (int j = 0; j < 4; j++)
    tile[ty + j * 8][tx] = W[(size_t)(bk + ty + j * 8) * DIM + bn + tx];
  __syncthreads();
#pragma unroll
  for (int j = 0; j < 4; j++)
    WT[(size_t)(bn + ty + j * 8) * DIM + bk + tx] = f2bf(tile[tx][ty + j * 8]);
}

// Concat bq|bk into one 2048-float bias for the fused QK projection.
__global__ __launch_bounds__(256)
void bcat(const float* __restrict__ a, const float* __restrict__ b,
          float* __restrict__ o)
{
  const int i = blockIdx.x * 256 + threadIdx.x;
  o[i] = (i < DIM) ? a[i] : b[i - DIM];
}

// ---------------------------------------------------------------------------
__global__ __launch_bounds__(256)
void assemble0(const float* __restrict__ seg0, short* __restrict__ X)
{
  const int Spad = SPMAX;
  const int b = blockIdx.y;
  const size_t lin = ((size_t)blockIdx.x * 256 + threadIdx.x) * 4;
  const int t = (int)(lin >> 10), d = (int)(lin & 1023);
  float4 v = make_float4(0.f, 0.f, 0.f, 0.f);
  if (t >= 1 && t <= SEQL)
    v = *(const float4*)(seg0 + ((size_t)b * SEQL + (t - 1)) * DIM + d);
  union { short s[4]; ull u; } o;
  o.s[0] = f2bf(v.x); o.s[1] = f2bf(v.y); o.s[2] = f2bf(v.z); o.s[3] = f2bf(v.w);
  *(ull*)(X + (size_t)b * Spad * DIM + lin) = o.u;
}

__global__ __launch_bounds__(256)
void assembleS(const float* __restrict__ seg1, const float* __restrict__ prompt,
               short* __restrict__ X)
{
  const int Spad = SPS;
  const int b = blockIdx.y;
  const size_t lin = ((size_t)blockIdx.x * 256 + threadIdx.x) * 4;
  const int t = (int)(lin >> 10), d = (int)(lin & 1023);
  float4 v = make_float4(0.f, 0.f, 0.f, 0.f);
  if (t == 0 || t == JSUM + 1)
    v = *(const float4*)(prompt + d);
  else if (t >= 1 && t <= JSUM)
    v = *(const float4*)(seg1 + ((size_t)b * SEQL + (t - 1)) * DIM + d);
  union { short s[4]; ull u; } o;
  o.s[0] = f2bf(v.x); o.s[1] = f2bf(v.y); o.s[2] = f2bf(v.z); o.s[3] = f2bf(v.w);
  *(ull*)(X + (size_t)b * Spad * DIM + lin) = o.u;
}

__global__ __launch_bounds__(256)
void assemble1(const float* __restrict__ seg0, const float* __restrict__ seg1,
               const float* __restrict__ P1, short* __restrict__ X)
{
  const int Spad = SPMAX;
  const int b = blockIdx.y;
  const size_t lin = ((size_t)blockIdx.x * 256 + threadIdx.x) * 4;
  const int t = (int)(lin >> 10), d = (int)(lin & 1023);
  float4 v = make_float4(0.f, 0.f, 0.f, 0.f);
  if (t < 32)
    v = *(const float4*)(seg0 + ((size_t)b * SEQL + (SEQL - 32 + t)) * DIM + d);
  else if (t == 32 || t == 2081)
    v = *(const float4*)(P1 + (size_t)b * DIM + d);
  else if (t >= 33 && t <= 2080)
    v = *(const float4*)(seg1 + ((size_t)b * SEQL + (t - 33)) * DIM + d);
  union { short s[4]; ull u; } o;
  o.s[0] = f2bf(v.x); o.s[1] = f2bf(v.y); o.s[2] = f2bf(v.z); o.s[3] = f2bf(v.w);
  *(ull*)(X + (size_t)b * Spad * DIM + lin) = o.u;
}

// ---------------------------------------------------------------------------
__global__ __launch_bounds__(256)
void mem_proj(const float* __restrict__ Sb, const float* __restrict__ M1,
              const float* __restrict__ Wq_mem, const float* __restrict__ bq_mem,
              const float* __restrict__ Wk_mem, const float* __restrict__ bk_mem,
              float* __restrict__ Qn, float* __restrict__ Kp)
{
  const int n = blockIdx.x * 256 + threadIdx.x;
  const int b = blockIdx.y;
  const int w = blockIdx.z;
  const float* x    = w ? M1 : Sb;
  const float* W    = w ? Wk_mem : Wq_mem;
  const float* bias = w ? bk_mem : bq_mem;
  float* o          = w ? Kp : Qn;
  const float* xr = x + (size_t)b * DIM;
  float s = bias[n];
  for (int k = 0; k < DIM; k++) s += xr[k] * W[(size_t)k * DIM + n];
  o[(size_t)b * DIM + n] = s;
}

__global__ __launch_bounds__(256)
void mem_attn(const float* __restrict__ Qn, const float* __restrict__ Kp,
              const float* __restrict__ M1, float* __restrict__ P1, float scale)
{
  __shared__ float red[256];
  __shared__ float w8[8];
  const int b = blockIdx.x, tid = threadIdx.x;
  for (int bp = 0; bp < NBATCH; bp++) {
    float p = 0.f;
    for (int k = tid; k < DIM; k += 256)
      p += Qn[(size_t)b * DIM + k] * Kp[(size_t)bp * DIM + k];
    red[tid] = p; __syncthreads();
    for (int off = 128; off; off >>= 1) {
      if (tid < off) red[tid] += red[tid + off];
      __syncthreads();
    }
    if (tid == 0) w8[bp] = red[0] * scale;
    __syncthreads();
  }
  if (tid == 0) {
    float m = w8[0];
    for (int i = 1; i < NBATCH; i++) m = fmaxf(m, w8[i]);
    float s = 0.f;
    for (int i = 0; i < NBATCH; i++) { w8[i] = __expf(w8[i] - m); s += w8[i]; }
    for (int i = 0; i < NBATCH; i++) w8[i] /= s;
  }
  __syncthreads();
  for (int d = tid; d < DIM; d += 256) {
    float a = 0.f;
    for (int bp = 0; bp < NBATCH; bp++) a += w8[bp] * M1[(size_t)bp * DIM + d];
    P1[(size_t)b * DIM + d] = a;
  }
}

// ---------------------------------------------------------------------------
extern "C" void kernel_launch(void* const* d_in, const int* in_sizes, int n_in,
                              void* d_out, int out_size, void* d_ws, size_t ws_size,
                              hipStream_t stream)
{
  const float* seg0   = (const float*)d_in[0];
  const float* seg1   = (const float*)d_in[1];
  const float* prompt = (const float*)d_in[2];
  const float* Wq_mem = (const float*)d_in[3];
  const float* bq_mem = (const float*)d_in[4];
  const float* Wk_mem = (const float*)d_in[5];
  const float* bk_mem = (const float*)d_in[6];
  const float* Wq     = (const float*)d_in[7];
  const float* bq     = (const float*)d_in[8];
  const float* Wk     = (const float*)d_in[9];
  const float* bk     = (const float*)d_in[10];
  const float* Wv     = (const float*)d_in[11];
  const float* bv     = (const float*)d_in[12];
  const float* Wo     = (const float*)d_in[13];
  const float* bo     = (const float*)d_in[14];
  float* outp = (float*)d_out;

  const size_t WSZ   = (size_t)DIM * DIM * 2;
  const size_t XSZ   = (size_t)NBATCH * SPMAX * DIM * 2;
  const size_t SASZ  = (size_t)NBATCH * SPMAX * SPMAX * 2;
  const size_t XSZS  = (size_t)NBATCH * SPS * DIM * 2;
  const size_t SASZS = (size_t)NBATCH * SPS * SPS * 2;
  const size_t VSZ   = (size_t)NBATCH * DIM * 4;

  char* p = (char*)d_ws;
  short* WqT  = (short*)p; p += WSZ;     // WqT and WkT contiguous -> fused QK
  short* WkT  = (short*)p; p += WSZ;
  short* WvT  = (short*)p; p += WSZ;
  short* WoT  = (short*)p; p += WSZ;
  short* X    = (short*)p; p += XSZ;
  short* QKb  = (short*)p; p += 2 * XSZ;   // fused Q|K, row stride 2048
  short* Vt   = (short*)p; p += XSZ;
  short* Ctx  = (short*)p; p += XSZ;
  short* SA   = (short*)p; p += SASZ;
  short* XS   = (short*)p; p += XSZS;      // phase-S buffers (coexist with ph0)
  short* QKbS = (short*)p; p += 2 * XSZS;
  short* VtS  = (short*)p; p += XSZS;
  short* CtxS = (short*)p; p += XSZS;
  short* SAS  = (short*)p; p += SASZS;
  float* M1b  = (float*)p; p += VSZ;
  float* Sb   = (float*)p; p += VSZ;
  float* Qn   = (float*)p; p += VSZ;
  float* Kp   = (float*)p; p += VSZ;
  float* P1   = (float*)p; p += VSZ;
  float* bqk  = (float*)p; p += 2 * DIM * 4;

  const float scale = 0.03125f;   // 1/sqrt(1024)
  dim3 blk(256, 1, 1);
  dim3 blkG(512, 1, 1);

  auto P = [](const short* A, ull sA, int ldA,
              const short* B, ull sB, int ldB,
              short* C, ull sC, int N, int Kd, const float* bias,
              float* dst0, int t_lo, int t_hi, int outT,
              float* dstSp, int t_sp, int Spad, int gx, int nblk) {
    GemmP q{A, sA, ldA, B, sB, ldB, C, sC, N, Kd, bias,
            dst0, t_lo, t_hi, outT, dstSp, t_sp, Spad, gx, nblk};
    return q;
  };

  wtrans<<<dim3(32, 32), blk, 0, stream>>>(Wq, WqT);
  wtrans<<<dim3(32, 32), blk, 0, stream>>>(Wk, WkT);
  wtrans<<<dim3(32, 32), blk, 0, stream>>>(Wv, WvT);
  wtrans<<<dim3(32, 32), blk, 0, stream>>>(Wo, WoT);
  bcat<<<dim3(8), blk, 0, stream>>>(bq, bk, bqk);

  // ---- Phase 0 (S=2050, Spad=2304) merged with Phase S (S=514, Spad=768).
  // Phase S depends only on seg1+prompt -> independent of phase 0 until
  // mem_proj; its small grids pack into phase-0's tail rounds.
  assemble0<<<dim3(SPMAX, NBATCH), blk, 0, stream>>>(seg0, X);
  assembleS<<<dim3(SPS, NBATCH), blk, 0, stream>>>(seg1, prompt, XS);

  {
    // Fused [Q|K] projection (MODE1, SWIZ2): ph0 576 blocks + phS 192.
    GemmP a = P(X, 0, DIM, WqT, 0, DIM, QKb, 0, 2048, DIM, bqk,
                nullptr, 0, 0, 0, nullptr, -1, SPMAX, NBATCH * SPMAX / 256, 576);
    GemmP b = P(XS, 0, DIM, WqT, 0, DIM, QKbS, 0, 2048, DIM, bqk,
                nullptr, 0, 0, 0, nullptr, -1, SPS, NBATCH * SPS / 256, 192);
    gemm_nt<1, 2><<<dim3(768), blkG, 0, stream>>>(a, b);
  }
  {
    // Vt = NT(WvT, X) + bv[m]  (MODE2, SWIZ1): 288 + 96.
    GemmP a = P(WvT, 0, DIM, X, (ull)SPMAX * DIM, DIM,
                Vt, (ull)DIM * SPMAX, SPMAX, DIM, bv,
                nullptr, 0, 0, 0, nullptr, -1, SPMAX, SPMAX / 256, 288);
    GemmP b = P(WvT, 0, DIM, XS, (ull)SPS * DIM, DIM,
                VtS, (ull)DIM * SPS, SPS, DIM, bv,
                nullptr, 0, 0, 0, nullptr, -1, SPS, SPS / 256, 96);
    gemm_nt<2, 1><<<dim3(384), blkG, 0, stream>>>(a, b);
  }
  {
    // scores = Q K^T  (MODE0, SWIZ1): 648 + 72.
    GemmP a = P(QKb, (ull)SPMAX * 2048, 2048, QKb + DIM, (ull)SPMAX * 2048, 2048,
                SA, (ull)SPMAX * SPMAX, SPMAX, DIM, nullptr,
                nullptr, 0, 0, 0, nullptr, -1, SPMAX, SPMAX / 256, 648);
    GemmP b = P(QKbS, (ull)SPS * 2048, 2048, QKbS + DIM, (ull)SPS * 2048, 2048,
                SAS, (ull)SPS * SPS, SPS, DIM, nullptr,
                nullptr, 0, 0, 0, nullptr, -1, SPS, SPS / 256, 72);
    gemm_nt<0, 1><<<dim3(720), blkG, 0, stream>>>(a, b);
  }
  softmax_rows2<<<dim3(SPMAX + SPS, NBATCH), blk, 0, stream>>>(
      SA, SPMAX, 2050, SPMAX, SAS, SPS, 514, scale);
  {
    // ctx = attn Vt^T  (MODE0, SWIZ1), K-trimmed: 288 (K=2112) + 96 (K=576).
    GemmP a = P(SA, (ull)SPMAX * SPMAX, SPMAX, Vt, (ull)DIM * SPMAX, SPMAX,
                Ctx, (ull)SPMAX * DIM, DIM, 2112, nullptr,
                nullptr, 0, 0, 0, nullptr, -1, SPMAX, DIM / 256, 288);
    GemmP b = P(SAS, (ull)SPS * SPS, SPS, VtS, (ull)DIM * SPS, SPS,
                CtxS, (ull)SPS * DIM, DIM, 576, nullptr,
                nullptr, 0, 0, 0, nullptr, -1, SPS, DIM / 256, 96);
    gemm_nt<0, 1><<<dim3(384), blkG, 0, stream>>>(a, b);
  }
  {
    // H = ctx Wo^T + bo, scattered (MODE3, SWIZ2): 288 + 96.
    GemmP a = P(Ctx, 0, DIM, WoT, 0, DIM, nullptr, 0, DIM, DIM, bo,
                outp, 33, 2049, 2016, M1b, 2049, SPMAX, NBATCH * SPMAX / 256, 288);
    GemmP b = P(CtxS, 0, DIM, WoT, 0, DIM, nullptr, 0, DIM, DIM, bo,
                nullptr, 0, 0, 0, Sb, JSUM, SPS, NBATCH * SPS / 256, 96);
    gemm_nt<3, 2><<<dim3(384), blkG, 0, stream>>>(a, b);
  }

  // ---- Memory attention (exact f32)
  mem_proj<<<dim3(DIM / 256, NBATCH, 2), blk, 0, stream>>>(
      Sb, M1b, Wq_mem, bq_mem, Wk_mem, bk_mem, Qn, Kp);
  mem_attn<<<dim3(NBATCH), blk, 0, stream>>>(Qn, Kp, M1b, P1, scale);

  // ---- Phase 1: backbone([seg0[-32:], P1, seg1, P1])  S=2082, Spad=2304
  assemble1<<<dim3(SPMAX, NBATCH), blk, 0, stream>>>(seg0, seg1, P1, X);
  {
    GemmP a = P(X, 0, DIM, WqT, 0, DIM, QKb, 0, 2048, DIM, bqk,
                nullptr, 0, 0, 0, nullptr, -1, SPMAX, NBATCH * SPMAX / 256, 576);
    gemm_nt<1, 2><<<dim3(576), blkG, 0, stream>>>(a, a);
  }
  {
    GemmP a = P(WvT, 0, DIM, X, (ull)SPMAX * DIM, DIM,
                Vt, (ull)DIM * SPMAX, SPMAX, DIM, bv,
                nullptr, 0, 0, 0, nullptr, -1, SPMAX, SPMAX / 256, 288);
    gemm_nt<2, 1><<<dim3(288), blkG, 0, stream>>>(a, a);
  }
  {
    GemmP a = P(QKb, (ull)SPMAX * 2048, 2048, QKb + DIM, (ull)SPMAX * 2048, 2048,
                SA, (ull)SPMAX * SPMAX, SPMAX, DIM, nullptr,
                nullptr, 0, 0, 0, nullptr, -1, SPMAX, SPMAX / 256, 648);
    gemm_nt<0, 1><<<dim3(648), blkG, 0, stream>>>(a, a);
  }
  softmax_rows2<<<dim3(SPMAX, NBATCH), blk, 0, stream>>>(
      SA, SPMAX, 2082, SPMAX, SA, SPMAX, 2082, scale);
  {
    GemmP a = P(SA, (ull)SPMAX * SPMAX, SPMAX, Vt, (ull)DIM * SPMAX, SPMAX,
                Ctx, (ull)SPMAX * DIM, DIM, 2112, nullptr,
                nullptr, 0, 0, 0, nullptr, -1, SPMAX, DIM / 256, 288);
    gemm_nt<0, 1><<<dim3(288), blkG, 0, stream>>>(a, a);
  }
  {
    GemmP a = P(Ctx, 0, DIM, WoT, 0, DIM, nullptr, 0, DIM, DIM, bo,
                outp + (size_t)NBATCH * 2016 * DIM, 33, 2081, 2048,
                nullptr, -1, SPMAX, NBATCH * SPMAX / 256, 288);
    gemm_nt<3, 2><<<dim3(288), blkG, 0, stream>>>(a, a);
  }
}